// Round 2
// baseline (25185.823 us; speedup 1.0000x reference)
//
#include <hip/hip_runtime.h>
#include <hip/hip_bf16.h>

#define NTH 256
#define KB 10   // k-chunk rows staged in LDS per GEMM step

// ---------------- prep kernels (rebuild ws every call; ws is re-poisoned) ----
// combined[k][c] = sum_m Wsel[k][m] * in_w[c][m], Wsel = Wq/Wk/Wv by c/160
__global__ void prep_combined(const float* __restrict__ Wq,
                              const float* __restrict__ Wk,
                              const float* __restrict__ Wv,
                              const float* __restrict__ in_w,
                              float* __restrict__ dst)
{
    int o = blockIdx.x*NTH + threadIdx.x;
    if (o >= 160*480) return;
    int k = o/480, c = o - k*480;
    const float* Wsel = (c<160) ? Wq : (c<320) ? Wk : Wv;
    const float* wrow = Wsel + k*160;
    const float* irow = in_w + c*160;
    float s = 0.f;
    for (int m=0;m<160;m++) s = fmaf(wrow[m], irow[m], s);
    dst[o] = s;
}

// dst[k*R + c] = src[c*160 + k]   (k<160, c<R): k-major transpose for streaming
__global__ void prep_transpose(const float* __restrict__ src, float* __restrict__ dst, int R)
{
    int o = blockIdx.x*NTH + threadIdx.x;
    if (o >= R*160) return;
    int k = o / R, c = o - k*R;
    dst[o] = src[c*160 + k];
}

// ---------------- fused per-node kernel ----------------
// LDS GEMM: dst(ROWS x 160) = src(ROWS x 160) @ Wg[:, colbase:colbase+160] + bias
// Wg is k-major (160 x ldW) fp32 in global; chunks of KB rows staged in sW.
// Thread tile: c0=(tid&31)*5 cols, rows rg+8u (rg=tid>>5), RT=ROWS/8 rows.
template<int ROWS>
__device__ void gemm_ld(const float* __restrict__ src,
                        const float* __restrict__ Wg, int ldW, int colbase,
                        const float* __restrict__ bias,
                        float* __restrict__ dst,
                        float* __restrict__ sW, int tid)
{
    constexpr int RT = ROWS/8;
    const int c0 = (tid & 31)*5;
    const int rg = tid >> 5;
    float acc[RT][5];
#pragma unroll
    for (int u=0;u<RT;u++)
#pragma unroll
        for (int q=0;q<5;q++) acc[u][q] = 0.f;

    for (int k0=0;k0<160;k0+=KB){
        for (int e=tid;e<KB*160;e+=NTH){
            int kk = e/160, c = e - kk*160;
            sW[e] = Wg[(k0+kk)*ldW + colbase + c];
        }
        __syncthreads();
#pragma unroll
        for (int i=0;i<KB;i++){
            float w[5];
#pragma unroll
            for (int q=0;q<5;q++) w[q] = sW[i*160 + c0 + q];
#pragma unroll
            for (int u=0;u<RT;u++){
                float s = src[(rg + 8*u)*160 + k0 + i];
#pragma unroll
                for (int q=0;q<5;q++) acc[u][q] = fmaf(s, w[q], acc[u][q]);
            }
        }
        __syncthreads();
    }
#pragma unroll
    for (int u=0;u<RT;u++){
#pragma unroll
        for (int q=0;q<5;q++)
            dst[(rg + 8*u)*160 + c0 + q] = acc[u][q] + bias[c0+q];
    }
    __syncthreads();
}

__global__ void __launch_bounds__(NTH)
gcn_node_kernel(const float* __restrict__ X,
                const int* __restrict__ in_idx,
                const int* __restrict__ out_idx,
                const float* __restrict__ ws,
                const float* __restrict__ i_in_b, const float* __restrict__ i_out_b,
                const float* __restrict__ o_in_b, const float* __restrict__ o_out_b,
                const float* __restrict__ f_in_b, const float* __restrict__ f_out_b,
                const float* __restrict__ lin_b,
                float* __restrict__ out)
{
    // LDS carve-up (fp32): total 15680 floats = 62720 B -> 2 blocks/CU
    __shared__ float sm[15680];
    __shared__ int sIdx[16];
    float* sA = sm;            // 5120 : a (32x160); later o2
    float* B1 = sm + 5120;     // 2560 : seq / fQ block
    float* B2 = sm + 7680;     // 2560 : Q,V / fK,fV low half
    float* B3 = sm + 10240;    // 2560 : K,o / fK,fV high half
    float* SS = sm + 12800;    // 1280 : scores / S2 / pooled
    float* sW = sm + 14080;    // 1600 : weight chunk (KB x 160)

    const int tid  = threadIdx.x;
    const int node = blockIdx.x;           // b*4096 + n
    const int bb   = node >> 12;
    const int nn   = node & 4095;

    // ---- two gather+attention layers (h=5, d=32) ----
    for (int layer=0; layer<2; layer++){
        const int*  idxp  = layer ? out_idx : in_idx;
        const float* Wqkv  = ws + (layer ? 76800 : 0);       // 160x480 combined
        const float* WoutT = ws + (layer ? 256000 : 230400); // 160x160
        const float* inb  = layer ? o_in_b  : i_in_b;
        const float* outb = layer ? o_out_b : i_out_b;

        if (tid < 16)
            sIdx[tid] = (tid==0) ? nn : idxp[node*15 + tid-1];
        __syncthreads();
        for (int e=tid;e<2560;e+=NTH){
            int r = e/160, c = e - r*160;
            B1[e] = X[(bb*4096 + sIdx[r])*160 + c];
        }
        __syncthreads();

        gemm_ld<16>(B1, Wqkv, 480, 0,   inb,     B2, sW, tid);  // Q
        gemm_ld<16>(B1, Wqkv, 480, 160, inb+160, B3, sW, tid);  // K

        // scores (5 heads, 16x16), scale = 1/sqrt(32)
        for (int o=tid;o<1280;o+=NTH){
            int h=o>>8, ij=o&255, i=ij>>4, j=ij&15;
            const float* q = B2 + i*160 + h*32;
            const float* k = B3 + j*160 + h*32;
            float s=0.f;
#pragma unroll
            for (int d=0;d<32;d++) s = fmaf(q[d],k[d],s);
            SS[o] = s * 0.17677669529663687f;
        }
        __syncthreads();
        if (tid < 80){                      // softmax over 80 rows of 16
            float* row = SS + tid*16;
            float m = row[0];
#pragma unroll
            for (int j=1;j<16;j++) m = fmaxf(m,row[j]);
            float sum=0.f, ev[16];
#pragma unroll
            for (int j=0;j<16;j++){ ev[j]=__expf(row[j]-m); sum+=ev[j]; }
            float inv = 1.f/sum;
#pragma unroll
            for (int j=0;j<16;j++) row[j] = ev[j]*inv;
        }
        __syncthreads();

        gemm_ld<16>(B1, Wqkv, 480, 320, inb+320, B2, sW, tid);  // V (over Q)

        // o = S @ V  -> B3 (over K)
        for (int o=tid;o<2560;o+=NTH){
            int r=o/160, c=o-r*160, h=c>>5;
            const float* srow = SS + h*256 + r*16;
            const float* v = B2 + c;
            float s=0.f;
#pragma unroll
            for (int j=0;j<16;j++) s = fmaf(srow[j], v[j*160], s);
            B3[o]=s;
        }
        __syncthreads();

        gemm_ld<16>(B3, WoutT, 160, 0, outb, sA + layer*2560, sW, tid);
    }

    // ---- final single-head MHA over the 32 rows of a ----
    const float* WfT = ws + 153600;                  // f_in_w^T, 160x480
    gemm_ld<32>(sA, WfT, 480, 160, f_in_b+160, B2, sW, tid);   // fK -> B2..B3

    for (int rb=0;rb<2;rb++){
        gemm_ld<16>(sA + rb*2560, WfT, 480, 0, f_in_b, B1, sW, tid);  // fQ block
        for (int o=tid;o<512;o+=NTH){                // S2 rows rb*16..rb*16+15
            int i=o>>5, j=o&31;
            const float* q = B1 + i*160;
            const float* k = B2 + j*160;
            float s=0.f;
            for (int d=0;d<160;d++) s = fmaf(q[d],k[d],s);
            SS[(rb*16+i)*32 + j] = s * 0.07905694150420949f;  // 1/sqrt(160)
        }
        __syncthreads();
    }
    if (tid<32){                                     // softmax, 32 rows of 32
        float* row = SS + tid*32;
        float m=row[0];
#pragma unroll
        for (int j=1;j<32;j++) m=fmaxf(m,row[j]);
        float sum=0.f, ev[32];
#pragma unroll
        for (int j=0;j<32;j++){ ev[j]=__expf(row[j]-m); sum+=ev[j]; }
        float inv=1.f/sum;
#pragma unroll
        for (int j=0;j<32;j++) row[j]=ev[j]*inv;
    }
    __syncthreads();

    gemm_ld<32>(sA, WfT, 480, 320, f_in_b+320, B2, sW, tid);   // fV (over fK)

    // o2 = S2 @ fV -> sA (a fully consumed)
    for (int o=tid;o<5120;o+=NTH){
        int r=o/160, c=o-r*160;
        const float* srow = SS + r*32;
        const float* v = B2 + c;
        float s=0.f;
#pragma unroll
        for (int j=0;j<32;j++) s = fmaf(srow[j], v[j*160], s);
        sA[o]=s;
    }
    __syncthreads();

    // fused f_out projection + max-pool over 32 rows: pooled[c]=max_l f[l][c]
    const float* WoF = ws + 281600;
    float facc[32];
#pragma unroll
    for (int l=0;l<32;l++) facc[l]=0.f;
    for (int k0=0;k0<160;k0+=KB){
        for (int e=tid;e<KB*160;e+=NTH){
            int kk=e/160, c=e-kk*160;
            sW[e] = WoF[(k0+kk)*160 + c];
        }
        __syncthreads();
        if (tid<160){
#pragma unroll
            for (int i=0;i<KB;i++){
                float w = sW[i*160+tid];
                const float* ocol = sA + (k0+i);
#pragma unroll
                for (int l=0;l<32;l++) facc[l] = fmaf(ocol[l*160], w, facc[l]);
            }
        }
        __syncthreads();
    }
    if (tid<160){
        float m = facc[0];
#pragma unroll
        for (int l=1;l<32;l++) m = fmaxf(m, facc[l]);
        SS[tid] = m + f_out_b[tid];   // pooled
    }
    __syncthreads();

    // final linear + ELU, WlinT streamed straight from L2
    const float* WlT = ws + 307200;
    if (tid<160){
        float acc=0.f;
        for (int k=0;k<160;k++) acc = fmaf(SS[k], WlT[k*160+tid], acc);
        acc += lin_b[tid];
        out[node*160 + tid] = acc>0.f ? acc : expm1f(acc);
    }
}

extern "C" void kernel_launch(void* const* d_in, const int* in_sizes, int n_in,
                              void* d_out, int out_size, void* d_ws, size_t ws_size,
                              hipStream_t stream)
{
    const float* X       = (const float*)d_in[0];
    const int*   in_idx  = (const int*)  d_in[1];
    const int*   out_idx = (const int*)  d_in[2];
    const float* iWq     = (const float*)d_in[3];
    const float* iWk     = (const float*)d_in[4];
    const float* iWv     = (const float*)d_in[5];
    const float* i_in_w  = (const float*)d_in[6];
    const float* i_in_b  = (const float*)d_in[7];
    const float* i_out_w = (const float*)d_in[8];
    const float* i_out_b = (const float*)d_in[9];
    const float* oWq     = (const float*)d_in[10];
    const float* oWk     = (const float*)d_in[11];
    const float* oWv     = (const float*)d_in[12];
    const float* o_in_w  = (const float*)d_in[13];
    const float* o_in_b  = (const float*)d_in[14];
    const float* o_out_w = (const float*)d_in[15];
    const float* o_out_b = (const float*)d_in[16];
    const float* f_in_w  = (const float*)d_in[17];
    const float* f_in_b  = (const float*)d_in[18];
    const float* f_out_w = (const float*)d_in[19];
    const float* f_out_b = (const float*)d_in[20];
    const float* lin_w   = (const float*)d_in[21];
    const float* lin_b   = (const float*)d_in[22];

    float* ws = (float*)d_ws;
    // ws layout (floats): Wqkv_i@0, Wqkv_o@76800, WfinT@153600,
    //   WoutT_i@230400, WoutT_o@256000, WoutT_f@281600, WlinT@307200  (1.33 MB)
    prep_combined<<<300,NTH,0,stream>>>(iWq,iWk,iWv,i_in_w, ws);
    prep_combined<<<300,NTH,0,stream>>>(oWq,oWk,oWv,o_in_w, ws+76800);
    prep_transpose<<<300,NTH,0,stream>>>(f_in_w,  ws+153600, 480);
    prep_transpose<<<100,NTH,0,stream>>>(i_out_w, ws+230400, 160);
    prep_transpose<<<100,NTH,0,stream>>>(o_out_w, ws+256000, 160);
    prep_transpose<<<100,NTH,0,stream>>>(f_out_w, ws+281600, 160);
    prep_transpose<<<100,NTH,0,stream>>>(lin_w,   ws+307200, 160);

    gcn_node_kernel<<<32768,NTH,0,stream>>>(X, in_idx, out_idx, ws,
        i_in_b, i_out_b, o_in_b, o_out_b, f_in_b, f_out_b, lin_b,
        (float*)d_out);
}

// Round 3
// 7727.570 us; speedup vs baseline: 3.2592x; 3.2592x over previous
//
#include <hip/hip_runtime.h>
#include <hip/hip_bf16.h>
#include <math.h>

#define NTH 256

// ============================ prep kernels ============================
// Wc[c][j] = sum_k Wsel[j][k] * in_w[c][k]   (Wsel by c: q/k/v), (480 x 160) n-major
__global__ void prep_combined(const float* __restrict__ Wq, const float* __restrict__ Wk,
                              const float* __restrict__ Wv, const float* __restrict__ in_w,
                              float* __restrict__ dst)
{
    int o = blockIdx.x*NTH + threadIdx.x;
    if (o >= 76800) return;
    int c = o/160, j = o - c*160;
    const float* Wsel = (c<160) ? Wq : (c<320) ? Wk : Wv;
    const float* wrow = Wsel + j*160;
    const float* irow = in_w + c*160;
    float s = 0.f;
    for (int k=0;k<160;k++) s = fmaf(wrow[k], irow[k], s);
    dst[o] = s;
}

// H[n][k] = sum_c f_in_w[n][c] * out_w[c][k]   (480 x 160) n-major
__global__ void prep_H(const float* __restrict__ f_in_w, const float* __restrict__ out_w,
                       float* __restrict__ H)
{
    int o = blockIdx.x*NTH + threadIdx.x;
    if (o >= 76800) return;
    int n = o/160, k = o - n*160;
    float s = 0.f;
    for (int c=0;c<160;c++) s = fmaf(f_in_w[n*160+c], out_w[c*160+k], s);
    H[o] = s;
}

// cv[n] = f_in_w[n] . out_b + f_in_b[n]
__global__ void prep_cvec(const float* __restrict__ f_in_w, const float* __restrict__ out_b,
                          const float* __restrict__ f_in_b, float* __restrict__ cv)
{
    int n = blockIdx.x*NTH + threadIdx.x;
    if (n >= 480) return;
    float s = f_in_b[n];
    for (int c=0;c<160;c++) s = fmaf(f_in_w[n*160+c], out_b[c], s);
    cv[n] = s;
}

// ============================ dense GEMM ============================
// C(M x N) = A(M x 160) @ W(N x 160)^T + bias.  Block tile 64M x 80N, K-chunks of 16.
// Thread (tx 0..15, ty 0..15): 4 rows (ty*4+i) x 5 cols (tx*5+j).
// EPI: 0 = bias store, 1 = bias+ELU store, 2 = maxpool over 32-row node groups:
//      writes pooled[(node_base + blk.x*2 + g)*160 + n0 + col] = max_rows + bias.
template<int EPI>
__global__ __launch_bounds__(NTH)
void gemm160(const float* __restrict__ A, const float* __restrict__ W,
             const float* __restrict__ bias, float* __restrict__ C,
             int N, int node_base)
{
    __shared__ float sA[64*20];   // padded stride 20 (float4-aligned, 2-way max)
    __shared__ float sW[80*20];
    const int tid = threadIdx.x;
    const int tx = tid & 15, ty = tid >> 4;
    const long m0 = (long)blockIdx.x * 64;
    const int  n0 = blockIdx.y * 80;

    float acc[4][5];
#pragma unroll
    for (int i=0;i<4;i++)
#pragma unroll
        for (int j=0;j<5;j++) acc[i][j] = 0.f;

    for (int k0=0;k0<160;k0+=16){
        { // stage A: 64x16, one float4/thread
            int m = tid>>2, kc = (tid&3)*4;
            float4 v = *(const float4*)(A + (m0+m)*160 + k0 + kc);
            float* p = sA + m*20 + kc;
            p[0]=v.x; p[1]=v.y; p[2]=v.z; p[3]=v.w;
        }
        for (int e=tid;e<1280;e+=NTH){ // stage W: 80x16
            int n = e>>4, kc = e&15;
            sW[n*20+kc] = W[(long)(n0+n)*160 + k0 + kc];
        }
        __syncthreads();
#pragma unroll
        for (int kk=0;kk<16;kk++){
            float a[4], w[5];
#pragma unroll
            for (int i=0;i<4;i++) a[i] = sA[(ty*4+i)*20 + kk];
#pragma unroll
            for (int j=0;j<5;j++) w[j] = sW[(tx*5+j)*20 + kk];
#pragma unroll
            for (int i=0;i<4;i++)
#pragma unroll
                for (int j=0;j<5;j++) acc[i][j] = fmaf(a[i], w[j], acc[i][j]);
        }
        __syncthreads();
    }

    if (EPI == 2){
        // per-thread max over its 4 rows (all within one 32-row node: ty*4..ty*4+3)
        float* red = sA;   // 16 x 80 = 1280 floats, fits
        float lm[5];
#pragma unroll
        for (int j=0;j<5;j++){
            float m = acc[0][j];
#pragma unroll
            for (int i=1;i<4;i++) m = fmaxf(m, acc[i][j]);
            lm[j] = m;
        }
#pragma unroll
        for (int j=0;j<5;j++) red[ty*80 + tx*5 + j] = lm[j];
        __syncthreads();
        if (tid < 160){
            int g = tid / 80, col = tid - g*80;
            float m = red[(g*8)*80 + col];
#pragma unroll
            for (int t=1;t<8;t++) m = fmaxf(m, red[(g*8+t)*80 + col]);
            int node = node_base + blockIdx.x*2 + g;
            C[(long)node*160 + n0 + col] = m + bias[n0 + col];
        }
    } else {
#pragma unroll
        for (int i=0;i<4;i++){
            long row = m0 + ty*4 + i;
            float* crow = C + row*N + n0;
#pragma unroll
            for (int j=0;j<5;j++){
                float x = acc[i][j] + bias[n0 + tx*5 + j];
                if (EPI == 1) x = x > 0.f ? x : expm1f(x);
                crow[tx*5 + j] = x;
            }
        }
    }
}

// ============================ per-node attention, layers 1/2 ============================
// One block per node: gather 16 rows of XP (self + 15 neighbors), 5-head 16x16 attn,
// write O rows (node_local*16 + r) x 160.
__global__ __launch_bounds__(NTH)
void attn_layer(const float* __restrict__ XP, const int* __restrict__ idx,
                float* __restrict__ O, int node_base)
{
    __shared__ float XPg[16*484];   // padded stride 484 (484%32=4 -> 2-way max)
    __shared__ float SS[80*17];     // padded stride 17
    __shared__ int sIdx[16];
    const int tid = threadIdx.x;
    const int nl  = blockIdx.x;
    const int node = node_base + nl;
    const int bb = node >> 12, nn = node & 4095;

    if (tid < 16) sIdx[tid] = (tid==0) ? nn : idx[(long)node*15 + tid-1];
    __syncthreads();
    for (int e=tid;e<1920;e+=NTH){
        int r = e/120, c4 = e - r*120;
        float4 v = *(const float4*)(XP + (long)(bb*4096 + sIdx[r])*480 + c4*4);
        *(float4*)(XPg + r*484 + c4*4) = v;
    }
    __syncthreads();
    for (int o=tid;o<1280;o+=NTH){          // scores: 5h x 16 x 16, d=32
        int h=o>>8, ij=o&255, i=ij>>4, j=ij&15;
        const float* q = XPg + i*484 + h*32;
        const float* k = XPg + j*484 + 160 + h*32;
        float s = 0.f;
#pragma unroll
        for (int d=0;d<32;d++) s = fmaf(q[d], k[d], s);
        SS[(h*16+i)*17 + j] = s * 0.17677669529663687f;   // 1/sqrt(32)
    }
    __syncthreads();
    if (tid < 80){                           // softmax, 80 rows of 16
        float* row = SS + tid*17;
        float m = row[0];
#pragma unroll
        for (int j=1;j<16;j++) m = fmaxf(m, row[j]);
        float sum=0.f, ev[16];
#pragma unroll
        for (int j=0;j<16;j++){ ev[j]=__expf(row[j]-m); sum+=ev[j]; }
        float inv = 1.f/sum;
#pragma unroll
        for (int j=0;j<16;j++) row[j] = ev[j]*inv;
    }
    __syncthreads();
    for (int o=tid;o<2560;o+=NTH){          // O = S @ V, 16 x 160
        int r=o/160, c=o-r*160, h=c>>5;
        const float* srow = SS + (h*16+r)*17;
        const float* v = XPg + 320 + c;
        float s = 0.f;
#pragma unroll
        for (int j=0;j<16;j++) s = fmaf(srow[j], v[j*484], s);
        O[(long)(nl*16+r)*160 + c] = s;
    }
}

// ============================ per-node final attention ============================
// One block per node: F rows 0-15 from FQi, 16-31 from FQo (each 480 = [fq|fk|fv]),
// single-head 32x32 attention (d=160), write O2 (node_local*32 + r) x 160.
__global__ __launch_bounds__(NTH)
void attn_final(const float* __restrict__ FQi, const float* __restrict__ FQo,
                float* __restrict__ O2)
{
    __shared__ float F[32*484];
    __shared__ float S2[32*33];
    const int tid = threadIdx.x;
    const int nl  = blockIdx.x;

    for (int e=tid;e<3840;e+=NTH){
        int r = e/120, c4 = e - r*120;
        const float* src = (r<16) ? (FQi + (long)(nl*16+r)*480)
                                  : (FQo + (long)(nl*16+r-16)*480);
        *(float4*)(F + r*484 + c4*4) = *(const float4*)(src + c4*4);
    }
    __syncthreads();
    for (int o=tid;o<1024;o+=NTH){          // S2: 32x32, d=160
        int i=o>>5, j=o&31;
        const float* q = F + i*484;
        const float* k = F + j*484 + 160;
        float s = 0.f;
        for (int d=0;d<160;d++) s = fmaf(q[d], k[d], s);
        S2[i*33 + j] = s * 0.07905694150420949f;          // 1/sqrt(160)
    }
    __syncthreads();
    if (tid < 32){                           // softmax, 32 rows of 32
        float* row = S2 + tid*33;
        float m = row[0];
#pragma unroll
        for (int j=1;j<32;j++) m = fmaxf(m, row[j]);
        float sum=0.f, ev[32];
#pragma unroll
        for (int j=0;j<32;j++){ ev[j]=__expf(row[j]-m); sum+=ev[j]; }
        float inv = 1.f/sum;
#pragma unroll
        for (int j=0;j<32;j++) row[j] = ev[j]*inv;
    }
    __syncthreads();
    for (int o=tid;o<5120;o+=NTH){          // O2 = S2 @ fV, 32 x 160
        int r=o/160, c=o-r*160;
        const float* srow = S2 + r*33;
        const float* v = F + 320 + c;
        float s = 0.f;
#pragma unroll
        for (int j=0;j<32;j++) s = fmaf(srow[j], v[j*484], s);
        O2[(long)(nl*32+r)*160 + c] = s;
    }
}

// ============================ host ============================
extern "C" void kernel_launch(void* const* d_in, const int* in_sizes, int n_in,
                              void* d_out, int out_size, void* d_ws, size_t ws_size,
                              hipStream_t stream)
{
    const float* X       = (const float*)d_in[0];
    const int*   in_idx  = (const int*)  d_in[1];
    const int*   out_idx = (const int*)  d_in[2];
    const float* iWq     = (const float*)d_in[3];
    const float* iWk     = (const float*)d_in[4];
    const float* iWv     = (const float*)d_in[5];
    const float* i_in_w  = (const float*)d_in[6];
    const float* i_in_b  = (const float*)d_in[7];
    const float* i_out_w = (const float*)d_in[8];
    const float* i_out_b = (const float*)d_in[9];
    const float* oWq     = (const float*)d_in[10];
    const float* oWk     = (const float*)d_in[11];
    const float* oWv     = (const float*)d_in[12];
    const float* o_in_w  = (const float*)d_in[13];
    const float* o_in_b  = (const float*)d_in[14];
    const float* o_out_w = (const float*)d_in[15];
    const float* o_out_b = (const float*)d_in[16];
    const float* f_in_w  = (const float*)d_in[17];
    const float* f_in_b  = (const float*)d_in[18];
    const float* f_out_w = (const float*)d_in[19];
    const float* f_out_b = (const float*)d_in[20];
    const float* lin_w   = (const float*)d_in[21];
    const float* lin_b   = (const float*)d_in[22];

    float* ws = (float*)d_ws;
    // fixed region
    float* Wc_i   = ws;                       // 76800
    float* Wc_o   = Wc_i + 76800;
    float* H_i    = Wc_o + 76800;
    float* H_o    = H_i  + 76800;
    float* c_i    = H_o  + 76800;             // 480
    float* c_o    = c_i  + 480;
    float* XP_i   = c_o  + 480;               // 32768*480
    float* XP_o   = XP_i + 15728640;
    float* pooled = XP_o + 15728640;          // 32768*160
    float* sbase  = pooled + 5242880;
    size_t fixed  = (size_t)(sbase - ws);     // 37,008,320 floats

    size_t avail = ws_size / 4;
    int ns = 4096;                            // nodes per slice
    while (ns > 256 && fixed + (size_t)25600*ns > avail) ns >>= 1;

    float* O_i = sbase;                       // ns*16*160
    float* O_o = O_i + (size_t)2560*ns;
    float* FQi = O_o + (size_t)2560*ns;       // ns*16*480
    float* FQo = FQi + (size_t)7680*ns;
    float* O2  = FQo + (size_t)7680*ns;       // ns*32*160

    // prep
    prep_combined<<<300,NTH,0,stream>>>(iWq,iWk,iWv,i_in_w, Wc_i);
    prep_combined<<<300,NTH,0,stream>>>(oWq,oWk,oWv,o_in_w, Wc_o);
    prep_H<<<300,NTH,0,stream>>>(f_in_w, i_out_w, H_i);
    prep_H<<<300,NTH,0,stream>>>(f_in_w, o_out_w, H_o);
    prep_cvec<<<2,NTH,0,stream>>>(f_in_w, i_out_b, f_in_b, c_i);
    prep_cvec<<<2,NTH,0,stream>>>(f_in_w, o_out_b, f_in_b, c_o);

    // XP = X @ Wc^T + in_b   (32768 x 480)
    dim3 g1(512, 6);
    gemm160<0><<<g1,NTH,0,stream>>>(X, Wc_i, i_in_b, XP_i, 480, 0);
    gemm160<0><<<g1,NTH,0,stream>>>(X, Wc_o, o_in_b, XP_o, 480, 0);

    int S = 32768 / ns;
    for (int s=0;s<S;s++){
        int base = s*ns;
        attn_layer<<<ns,NTH,0,stream>>>(XP_i, in_idx,  O_i, base);
        attn_layer<<<ns,NTH,0,stream>>>(XP_o, out_idx, O_o, base);
        dim3 g3(ns*16/64, 6);
        gemm160<0><<<g3,NTH,0,stream>>>(O_i, H_i, c_i, FQi, 480, 0);
        gemm160<0><<<g3,NTH,0,stream>>>(O_o, H_o, c_o, FQo, 480, 0);
        attn_final<<<ns,NTH,0,stream>>>(FQi, FQo, O2);
        dim3 g5(ns*32/64, 2);
        gemm160<2><<<g5,NTH,0,stream>>>(O2, f_out_w, f_out_b, pooled, 160, base);
    }

    // out = ELU(pooled @ lin_w^T + lin_b)
    dim3 g6(512, 2);
    gemm160<1><<<g6,NTH,0,stream>>>(pooled, lin_w, lin_b, (float*)d_out, 160, 0);
}

// Round 4
// 4867.932 us; speedup vs baseline: 5.1738x; 1.5874x over previous
//
#include <hip/hip_runtime.h>
#include <hip/hip_bf16.h>
#include <math.h>

#define NTH 256

typedef __bf16 bf16x8 __attribute__((ext_vector_type(8)));
typedef float  f32x4  __attribute__((ext_vector_type(4)));

__device__ __forceinline__ unsigned short f2bf(float x){
    union { float f; unsigned int u; } v; v.f = x;
    unsigned int r = v.u + 0x7fffu + ((v.u >> 16) & 1u);
    return (unsigned short)(r >> 16);
}
__device__ __forceinline__ float bf2f(unsigned short h){
    union { unsigned int u; float f; } v; v.u = ((unsigned int)h) << 16;
    return v.f;
}

// ============================ prep kernels ============================
// Wc[c][j] = sum_k Wsel[j][k]*in_w[c][k]  -> bf16 hi/lo planes (480x160 row-major)
__global__ void prep_combined_bf(const float* __restrict__ Wq, const float* __restrict__ Wk,
                                 const float* __restrict__ Wv, const float* __restrict__ in_w,
                                 unsigned short* __restrict__ dh, unsigned short* __restrict__ dl)
{
    int o = blockIdx.x*NTH + threadIdx.x;
    if (o >= 76800) return;
    int c = o/160, j = o - c*160;
    const float* Wsel = (c<160) ? Wq : (c<320) ? Wk : Wv;
    const float* wrow = Wsel + j*160;
    const float* irow = in_w + c*160;
    float s = 0.f;
    for (int k=0;k<160;k++) s = fmaf(wrow[k], irow[k], s);
    unsigned short h = f2bf(s);
    dh[o] = h; dl[o] = f2bf(s - bf2f(h));
}

// H[n][k] = sum_c f_in_w[n][c]*out_w[c][k] -> hi/lo (480x160)
__global__ void prep_H_bf(const float* __restrict__ f_in_w, const float* __restrict__ out_w,
                          unsigned short* __restrict__ dh, unsigned short* __restrict__ dl)
{
    int o = blockIdx.x*NTH + threadIdx.x;
    if (o >= 76800) return;
    int n = o/160, k = o - n*160;
    float s = 0.f;
    for (int c=0;c<160;c++) s = fmaf(f_in_w[n*160+c], out_w[c*160+k], s);
    unsigned short h = f2bf(s);
    dh[o] = h; dl[o] = f2bf(s - bf2f(h));
}

// cv[n] = f_in_w[n].out_b + f_in_b[n]
__global__ void prep_cvec(const float* __restrict__ f_in_w, const float* __restrict__ out_b,
                          const float* __restrict__ f_in_b, float* __restrict__ cv)
{
    int n = blockIdx.x*NTH + threadIdx.x;
    if (n >= 480) return;
    float s = f_in_b[n];
    for (int c=0;c<160;c++) s = fmaf(f_in_w[n*160+c], out_b[c], s);
    cv[n] = s;
}

// straight fp32 -> bf16 hi/lo convert (for f_out_w, lin_w; 160x160)
__global__ void prep_conv_bf(const float* __restrict__ src,
                             unsigned short* __restrict__ dh, unsigned short* __restrict__ dl, int n)
{
    int o = blockIdx.x*NTH + threadIdx.x;
    if (o >= n) return;
    float s = src[o];
    unsigned short h = f2bf(s);
    dh[o] = h; dl[o] = f2bf(s - bf2f(h));
}

// ============================ MFMA GEMM ============================
// C(M x N) = A(M x 160) @ W(N x 160)^T [+ bias]; split-bf16x3 MFMA.
// Block 256 thr = 4 waves; tile 128M x 160N; wave (wm,wn): 64M x 80N.
// grid: (M/128, N/160, 1 or 2)  — z selects pointer set (merged dispatches).
// EPI: 0 = +bias store, 1 = +bias,ELU store, 2 = plain store (no bias).
template<int EPI>
__global__ __launch_bounds__(NTH)
void gemm_mfma(const float* __restrict__ A0, const float* __restrict__ A1,
               const unsigned short* __restrict__ Wh0, const unsigned short* __restrict__ Wl0,
               const unsigned short* __restrict__ Wh1, const unsigned short* __restrict__ Wl1,
               const float* __restrict__ b0, const float* __restrict__ b1,
               float* __restrict__ C0, float* __restrict__ C1, int N)
{
    const int z = blockIdx.z;
    const float* A = z ? A1 : A0;
    const unsigned short* Wh = z ? Wh1 : Wh0;
    const unsigned short* Wl = z ? Wl1 : Wl0;
    const float* bias = z ? b1 : b0;
    float* C = z ? C1 : C0;

    __shared__ unsigned short sAh[128*40], sAl[128*40];   // k-chunk 32, pad->40
    __shared__ unsigned short sWh[160*40], sWl[160*40];

    const int tid = threadIdx.x;
    const int lane = tid & 63, wave = tid >> 6;
    const int wm = wave >> 1, wn = wave & 1;
    const int ln = lane & 15, g = lane >> 4;
    const long m0 = (long)blockIdx.x * 128;
    const int  n0 = blockIdx.y * 160;

    f32x4 acc[4][5];
#pragma unroll
    for (int mt=0;mt<4;mt++)
#pragma unroll
        for (int nt=0;nt<5;nt++)
#pragma unroll
            for (int r=0;r<4;r++) acc[mt][nt][r] = 0.f;

    for (int k0=0;k0<160;k0+=32){
        // stage A (128x32 fp32 -> hi/lo bf16)
#pragma unroll
        for (int i=0;i<4;i++){
            int f = tid + 256*i;              // 0..1023 float4s
            int m = f >> 3, seg = f & 7;
            float4 v = *(const float4*)(A + (m0+m)*160 + k0 + seg*4);
            ushort4 hv, lv;
            hv.x = f2bf(v.x); lv.x = f2bf(v.x - bf2f(hv.x));
            hv.y = f2bf(v.y); lv.y = f2bf(v.y - bf2f(hv.y));
            hv.z = f2bf(v.z); lv.z = f2bf(v.z - bf2f(hv.z));
            hv.w = f2bf(v.w); lv.w = f2bf(v.w - bf2f(hv.w));
            *(ushort4*)(sAh + m*40 + seg*4) = hv;
            *(ushort4*)(sAl + m*40 + seg*4) = lv;
        }
        // stage W (160x32 bf16 hi/lo, pre-packed): 1280 uint4 copies
#pragma unroll
        for (int i=0;i<5;i++){
            int e = tid + 256*i;              // 0..1279
            int pl = (e >= 640);
            int idx = pl ? e-640 : e;
            int n = idx >> 2, seg = idx & 3;
            const unsigned short* src = (pl ? Wl : Wh) + (long)(n0+n)*160 + k0 + seg*8;
            unsigned short* dst = (pl ? sWl : sWh) + n*40 + seg*8;
            *(uint4*)dst = *(const uint4*)src;
        }
        __syncthreads();

        bf16x8 ah[4], al[4];
#pragma unroll
        for (int mt=0;mt<4;mt++){
            int off = (wm*64 + mt*16 + ln)*40 + g*8;
            ah[mt] = *(const bf16x8*)(sAh + off);
            al[mt] = *(const bf16x8*)(sAl + off);
        }
#pragma unroll
        for (int nt=0;nt<5;nt++){
            int offw = (wn*80 + nt*16 + ln)*40 + g*8;
            bf16x8 bh = *(const bf16x8*)(sWh + offw);
            bf16x8 bl = *(const bf16x8*)(sWl + offw);
#pragma unroll
            for (int mt=0;mt<4;mt++){
                acc[mt][nt] = __builtin_amdgcn_mfma_f32_16x16x32_bf16(ah[mt], bh, acc[mt][nt], 0,0,0);
                acc[mt][nt] = __builtin_amdgcn_mfma_f32_16x16x32_bf16(ah[mt], bl, acc[mt][nt], 0,0,0);
                acc[mt][nt] = __builtin_amdgcn_mfma_f32_16x16x32_bf16(al[mt], bh, acc[mt][nt], 0,0,0);
            }
        }
        __syncthreads();
    }

    // epilogue: C/D layout col=lane&15, row=(lane>>4)*4+reg
#pragma unroll
    for (int nt=0;nt<5;nt++){
        int col = n0 + wn*80 + nt*16 + ln;
        float bv = (EPI==2) ? 0.f : bias[col];
#pragma unroll
        for (int mt=0;mt<4;mt++){
#pragma unroll
            for (int r=0;r<4;r++){
                long row = m0 + wm*64 + mt*16 + g*4 + r;
                float x = acc[mt][nt][r] + bv;
                if (EPI==1) x = x > 0.f ? x : expm1f(x);
                C[row*N + col] = x;
            }
        }
    }
}

// ============================ per-node attention, layers 1/2 ============================
// grid (ns, 2): y selects in/out layer set. One block per node.
__global__ __launch_bounds__(NTH)
void attn_layer(const float* __restrict__ XPi, const float* __restrict__ XPo,
                const int* __restrict__ in_idx, const int* __restrict__ out_idx,
                float* __restrict__ Oi, float* __restrict__ Oo, int node_base)
{
    const float* XP = blockIdx.y ? XPo : XPi;
    const int*  idx = blockIdx.y ? out_idx : in_idx;
    float* O        = blockIdx.y ? Oo : Oi;

    __shared__ float XPg[16*484];
    __shared__ float SS[80*17];
    __shared__ int sIdx[16];
    const int tid = threadIdx.x;
    const int nl  = blockIdx.x;
    const int node = node_base + nl;
    const int bb = node >> 12, nn = node & 4095;

    if (tid < 16) sIdx[tid] = (tid==0) ? nn : idx[(long)node*15 + tid-1];
    __syncthreads();
    for (int e=tid;e<1920;e+=NTH){
        int r = e/120, c4 = e - r*120;
        float4 v = *(const float4*)(XP + (long)(bb*4096 + sIdx[r])*480 + c4*4);
        *(float4*)(XPg + r*484 + c4*4) = v;
    }
    __syncthreads();
    for (int o=tid;o<1280;o+=NTH){
        int h=o>>8, ij=o&255, i=ij>>4, j=ij&15;
        const float* q = XPg + i*484 + h*32;
        const float* k = XPg + j*484 + 160 + h*32;
        float s = 0.f;
#pragma unroll
        for (int d=0;d<32;d++) s = fmaf(q[d], k[d], s);
        SS[(h*16+i)*17 + j] = s * 0.17677669529663687f;
    }
    __syncthreads();
    if (tid < 80){
        float* row = SS + tid*17;
        float m = row[0];
#pragma unroll
        for (int j=1;j<16;j++) m = fmaxf(m, row[j]);
        float sum=0.f, ev[16];
#pragma unroll
        for (int j=0;j<16;j++){ ev[j]=__expf(row[j]-m); sum+=ev[j]; }
        float inv = 1.f/sum;
#pragma unroll
        for (int j=0;j<16;j++) row[j] = ev[j]*inv;
    }
    __syncthreads();
    for (int o=tid;o<2560;o+=NTH){
        int r=o/160, c=o-r*160, h=c>>5;
        const float* srow = SS + (h*16+r)*17;
        const float* v = XPg + 320 + c;
        float s = 0.f;
#pragma unroll
        for (int j=0;j<16;j++) s = fmaf(srow[j], v[j*484], s);
        O[(long)(nl*16+r)*160 + c] = s;
    }
}

// ============================ per-node final attention ============================
__global__ __launch_bounds__(NTH)
void attn_final(const float* __restrict__ FQi, const float* __restrict__ FQo,
                float* __restrict__ O2)
{
    __shared__ float F[32*484];
    __shared__ float S2[32*33];
    const int tid = threadIdx.x;
    const int nl  = blockIdx.x;

    for (int e=tid;e<3840;e+=NTH){
        int r = e/120, c4 = e - r*120;
        const float* src = (r<16) ? (FQi + (long)(nl*16+r)*480)
                                  : (FQo + (long)(nl*16+r-16)*480);
        *(float4*)(F + r*484 + c4*4) = *(const float4*)(src + c4*4);
    }
    __syncthreads();
    for (int o=tid;o<1024;o+=NTH){
        int i=o>>5, j=o&31;
        const float* q = F + i*484;
        const float* k = F + j*484 + 160;
        float s = 0.f;
        for (int d=0;d<160;d++) s = fmaf(q[d], k[d], s);
        S2[i*33 + j] = s * 0.07905694150420949f;
    }
    __syncthreads();
    if (tid < 32){
        float* row = S2 + tid*33;
        float m = row[0];
#pragma unroll
        for (int j=1;j<32;j++) m = fmaxf(m, row[j]);
        float sum=0.f, ev[32];
#pragma unroll
        for (int j=0;j<32;j++){ ev[j]=__expf(row[j]-m); sum+=ev[j]; }
        float inv = 1.f/sum;
#pragma unroll
        for (int j=0;j<32;j++) row[j] = ev[j]*inv;
    }
    __syncthreads();
    for (int o=tid;o<5120;o+=NTH){
        int r=o/160, c=o-r*160;
        const float* srow = S2 + r*33;
        const float* v = F + 320 + c;
        float s = 0.f;
#pragma unroll
        for (int j=0;j<32;j++) s = fmaf(srow[j], v[j*484], s);
        O2[(long)(nl*32+r)*160 + c] = s;
    }
}

// ============================ maxpool (32 rows -> 1) + bias ============================
__global__ __launch_bounds__(192)
void maxpool_k(const float* __restrict__ O3, const float* __restrict__ f_out_b,
               float* __restrict__ pooled, int node_base)
{
    int nl = blockIdx.x, c = threadIdx.x;
    if (c >= 160) return;
    const float* p = O3 + (long)nl*5120 + c;
    float m = p[0];
#pragma unroll
    for (int r=1;r<32;r++) m = fmaxf(m, p[r*160]);
    pooled[(long)(node_base+nl)*160 + c] = m + f_out_b[c];
}

// ============================ host ============================
extern "C" void kernel_launch(void* const* d_in, const int* in_sizes, int n_in,
                              void* d_out, int out_size, void* d_ws, size_t ws_size,
                              hipStream_t stream)
{
    const float* X       = (const float*)d_in[0];
    const int*   in_idx  = (const int*)  d_in[1];
    const int*   out_idx = (const int*)  d_in[2];
    const float* iWq     = (const float*)d_in[3];
    const float* iWk     = (const float*)d_in[4];
    const float* iWv     = (const float*)d_in[5];
    const float* i_in_w  = (const float*)d_in[6];
    const float* i_in_b  = (const float*)d_in[7];
    const float* i_out_w = (const float*)d_in[8];
    const float* i_out_b = (const float*)d_in[9];
    const float* oWq     = (const float*)d_in[10];
    const float* oWk     = (const float*)d_in[11];
    const float* oWv     = (const float*)d_in[12];
    const float* o_in_w  = (const float*)d_in[13];
    const float* o_in_b  = (const float*)d_in[14];
    const float* o_out_w = (const float*)d_in[15];
    const float* o_out_b = (const float*)d_in[16];
    const float* f_in_w  = (const float*)d_in[17];
    const float* f_in_b  = (const float*)d_in[18];
    const float* f_out_w = (const float*)d_in[19];
    const float* f_out_b = (const float*)d_in[20];
    const float* lin_w   = (const float*)d_in[21];
    const float* lin_b   = (const float*)d_in[22];

    float* ws = (float*)d_ws;
    float* XP_i   = ws;                         // 32768*480
    float* XP_o   = XP_i + 15728640;
    float* pooled = XP_o + 15728640;            // 32768*160
    float* c_i    = pooled + 5242880;           // 480
    float* c_o    = c_i + 480;
    unsigned short* ub = (unsigned short*)(c_o + 480);
    unsigned short* Wci_h = ub;                 // 76800 each
    unsigned short* Wci_l = Wci_h + 76800;
    unsigned short* Wco_h = Wci_l + 76800;
    unsigned short* Wco_l = Wco_h + 76800;
    unsigned short* Hi_h  = Wco_l + 76800;
    unsigned short* Hi_l  = Hi_h  + 76800;
    unsigned short* Ho_h  = Hi_l  + 76800;
    unsigned short* Ho_l  = Ho_h  + 76800;
    unsigned short* fo_h  = Ho_l  + 76800;      // 25600 each
    unsigned short* fo_l  = fo_h  + 25600;
    unsigned short* li_h  = fo_l  + 25600;
    unsigned short* li_l  = li_h  + 25600;
    float* sbase = (float*)(li_l + 25600);
    const unsigned long long fixed = 37059520ULL;   // floats

    size_t avail = ws_size / 4;
    int ns = 2048;
    while (ns > 64 && fixed + 30720ULL*ns > avail) ns >>= 1;

    float* O_i = sbase;                         // ns*16*160
    float* O_o = O_i + (size_t)2560*ns;
    float* FQi = O_o + (size_t)2560*ns;         // ns*16*480
    float* FQo = FQi + (size_t)7680*ns;
    float* O2  = FQo + (size_t)7680*ns;         // ns*32*160
    float* O3  = O2  + (size_t)5120*ns;         // ns*32*160

    // prep
    prep_combined_bf<<<300,NTH,0,stream>>>(iWq,iWk,iWv,i_in_w, Wci_h, Wci_l);
    prep_combined_bf<<<300,NTH,0,stream>>>(oWq,oWk,oWv,o_in_w, Wco_h, Wco_l);
    prep_H_bf<<<300,NTH,0,stream>>>(f_in_w, i_out_w, Hi_h, Hi_l);
    prep_H_bf<<<300,NTH,0,stream>>>(f_in_w, o_out_w, Ho_h, Ho_l);
    prep_cvec<<<2,NTH,0,stream>>>(f_in_w, i_out_b, f_in_b, c_i);
    prep_cvec<<<2,NTH,0,stream>>>(f_in_w, o_out_b, f_in_b, c_o);
    prep_conv_bf<<<100,NTH,0,stream>>>(f_out_w, fo_h, fo_l, 25600);
    prep_conv_bf<<<100,NTH,0,stream>>>(lin_w,   li_h, li_l, 25600);

    // XP = X @ Wc^T + in_b  (both layers in one dispatch, z=2)
    dim3 g1(256, 3, 2);
    gemm_mfma<0><<<g1,NTH,0,stream>>>(X, X, Wci_h, Wci_l, Wco_h, Wco_l,
                                      i_in_b, o_in_b, XP_i, XP_o, 480);

    int S = 32768 / ns;
    for (int s=0;s<S;s++){
        int base = s*ns;
        dim3 ga(ns, 2);
        attn_layer<<<ga,NTH,0,stream>>>(XP_i, XP_o, in_idx, out_idx, O_i, O_o, base);
        dim3 g3(ns/8, 3, 2);
        gemm_mfma<0><<<g3,NTH,0,stream>>>(O_i, O_o, Hi_h, Hi_l, Ho_h, Ho_l,
                                          c_i, c_o, FQi, FQo, 480);
        attn_final<<<ns,NTH,0,stream>>>(FQi, FQo, O2);
        dim3 g4(ns/4, 1, 1);
        gemm_mfma<2><<<g4,NTH,0,stream>>>(O2, O2, fo_h, fo_l, fo_h, fo_l,
                                          nullptr, nullptr, O3, O3, 160);
        maxpool_k<<<ns,192,0,stream>>>(O3, f_out_b, pooled, base);
    }

    // out = ELU(pooled @ lin_w^T + lin_b)
    dim3 g6(256, 1, 1);
    gemm_mfma<1><<<g6,NTH,0,stream>>>(pooled, pooled, li_h, li_l, li_h, li_l,
                                      lin_b, lin_b, (float*)d_out, (float*)d_out, 160);
}

// Round 5
// 3204.396 us; speedup vs baseline: 7.8598x; 1.5191x over previous
//
#include <hip/hip_runtime.h>
#include <hip/hip_bf16.h>
#include <math.h>

#define NTH 256

typedef __bf16 bf16x8 __attribute__((ext_vector_type(8)));
typedef float  f32x4  __attribute__((ext_vector_type(4)));
typedef unsigned short ushort;

__device__ __forceinline__ ushort f2bf(float x){
    union { float f; unsigned int u; } v; v.f = x;
    unsigned int r = v.u + 0x7fffu + ((v.u >> 16) & 1u);
    return (ushort)(r >> 16);
}
__device__ __forceinline__ float bf2f(ushort h){
    union { unsigned int u; float f; } v; v.u = ((unsigned int)h) << 16;
    return v.f;
}

// ============================ prep kernels ============================
__global__ void prep_combined_bf(const float* __restrict__ Wq, const float* __restrict__ Wk,
                                 const float* __restrict__ Wv, const float* __restrict__ in_w,
                                 ushort* __restrict__ dh, ushort* __restrict__ dl)
{
    int o = blockIdx.x*NTH + threadIdx.x;
    if (o >= 76800) return;
    int c = o/160, j = o - c*160;
    const float* Wsel = (c<160) ? Wq : (c<320) ? Wk : Wv;
    const float* wrow = Wsel + j*160;
    const float* irow = in_w + c*160;
    float s = 0.f;
    for (int k=0;k<160;k++) s = fmaf(wrow[k], irow[k], s);
    ushort h = f2bf(s);
    dh[o] = h; dl[o] = f2bf(s - bf2f(h));
}

__global__ void prep_H_bf(const float* __restrict__ f_in_w, const float* __restrict__ out_w,
                          ushort* __restrict__ dh, ushort* __restrict__ dl)
{
    int o = blockIdx.x*NTH + threadIdx.x;
    if (o >= 76800) return;
    int n = o/160, k = o - n*160;
    float s = 0.f;
    for (int c=0;c<160;c++) s = fmaf(f_in_w[n*160+c], out_w[c*160+k], s);
    ushort h = f2bf(s);
    dh[o] = h; dl[o] = f2bf(s - bf2f(h));
}

__global__ void prep_cvec(const float* __restrict__ f_in_w, const float* __restrict__ out_b,
                          const float* __restrict__ f_in_b, float* __restrict__ cv)
{
    int n = blockIdx.x*NTH + threadIdx.x;
    if (n >= 480) return;
    float s = f_in_b[n];
    for (int c=0;c<160;c++) s = fmaf(f_in_w[n*160+c], out_b[c], s);
    cv[n] = s;
}

__global__ void prep_conv_bf(const float* __restrict__ src,
                             ushort* __restrict__ dh, ushort* __restrict__ dl, int n)
{
    int o = blockIdx.x*NTH + threadIdx.x;
    if (o >= n) return;
    float s = src[o];
    ushort h = f2bf(s);
    dh[o] = h; dl[o] = f2bf(s - bf2f(h));
}

// ============================ MFMA GEMM (fp32 A, split x3) — XP & final ============
// C(M x N) = A(M x 160) @ W(N x 160)^T + bias. Block 256 thr; tile 128M x 160N.
template<int EPI>   // 0: +bias, 1: +bias+ELU
__global__ __launch_bounds__(NTH)
void gemm_mfma(const float* __restrict__ A0, const float* __restrict__ A1,
               const ushort* __restrict__ Wh0, const ushort* __restrict__ Wl0,
               const ushort* __restrict__ Wh1, const ushort* __restrict__ Wl1,
               const float* __restrict__ b0, const float* __restrict__ b1,
               float* __restrict__ C0, float* __restrict__ C1, int N)
{
    const int z = blockIdx.z;
    const float* A = z ? A1 : A0;
    const ushort* Wh = z ? Wh1 : Wh0;
    const ushort* Wl = z ? Wl1 : Wl0;
    const float* bias = z ? b1 : b0;
    float* C = z ? C1 : C0;

    __shared__ ushort sAh[128*40], sAl[128*40];
    __shared__ ushort sWh[160*40], sWl[160*40];

    const int tid = threadIdx.x;
    const int lane = tid & 63, wave = tid >> 6;
    const int wm = wave >> 1, wn = wave & 1;
    const int ln = lane & 15, g = lane >> 4;
    const long m0 = (long)blockIdx.x * 128;
    const int  n0 = blockIdx.y * 160;

    f32x4 acc[4][5];
#pragma unroll
    for (int mt=0;mt<4;mt++)
#pragma unroll
        for (int nt=0;nt<5;nt++)
#pragma unroll
            for (int r=0;r<4;r++) acc[mt][nt][r] = 0.f;

    for (int k0=0;k0<160;k0+=32){
#pragma unroll
        for (int i=0;i<4;i++){
            int f = tid + 256*i;
            int m = f >> 3, seg = f & 7;
            float4 v = *(const float4*)(A + (m0+m)*160 + k0 + seg*4);
            ushort4 hv, lv;
            hv.x = f2bf(v.x); lv.x = f2bf(v.x - bf2f(hv.x));
            hv.y = f2bf(v.y); lv.y = f2bf(v.y - bf2f(hv.y));
            hv.z = f2bf(v.z); lv.z = f2bf(v.z - bf2f(hv.z));
            hv.w = f2bf(v.w); lv.w = f2bf(v.w - bf2f(hv.w));
            *(ushort4*)(sAh + m*40 + seg*4) = hv;
            *(ushort4*)(sAl + m*40 + seg*4) = lv;
        }
#pragma unroll
        for (int i=0;i<5;i++){
            int e = tid + 256*i;
            int pl = (e >= 640);
            int idx = pl ? e-640 : e;
            int n = idx >> 2, seg = idx & 3;
            const ushort* src = (pl ? Wl : Wh) + (long)(n0+n)*160 + k0 + seg*8;
            ushort* dst = (pl ? sWl : sWh) + n*40 + seg*8;
            *(uint4*)dst = *(const uint4*)src;
        }
        __syncthreads();

        bf16x8 ah[4], al[4];
#pragma unroll
        for (int mt=0;mt<4;mt++){
            int off = (wm*64 + mt*16 + ln)*40 + g*8;
            ah[mt] = *(const bf16x8*)(sAh + off);
            al[mt] = *(const bf16x8*)(sAl + off);
        }
#pragma unroll
        for (int nt=0;nt<5;nt++){
            int offw = (wn*80 + nt*16 + ln)*40 + g*8;
            bf16x8 bh = *(const bf16x8*)(sWh + offw);
            bf16x8 bl = *(const bf16x8*)(sWl + offw);
#pragma unroll
            for (int mt=0;mt<4;mt++){
                acc[mt][nt] = __builtin_amdgcn_mfma_f32_16x16x32_bf16(ah[mt], bh, acc[mt][nt], 0,0,0);
                acc[mt][nt] = __builtin_amdgcn_mfma_f32_16x16x32_bf16(ah[mt], bl, acc[mt][nt], 0,0,0);
                acc[mt][nt] = __builtin_amdgcn_mfma_f32_16x16x32_bf16(al[mt], bh, acc[mt][nt], 0,0,0);
            }
        }
        __syncthreads();
    }

#pragma unroll
    for (int nt=0;nt<5;nt++){
        int col = n0 + wn*80 + nt*16 + ln;
        float bv = bias[col];
#pragma unroll
        for (int mt=0;mt<4;mt++){
#pragma unroll
            for (int r=0;r<4;r++){
                long row = m0 + wm*64 + mt*16 + g*4 + r;
                float x = acc[mt][nt][r] + bv;
                if (EPI==1) x = x > 0.f ? x : expm1f(x);
                C[row*N + col] = x;
            }
        }
    }
}

// ============================ FQ GEMM: A bf16 resident, W streamed ============
// C(M x 480) = A(M x 160, bf16) @ W(480 x 160)^T + bias -> bf16.
// 512 thr = 8 waves; block tile 128M x 480N; wave tile 32M x 240N.
__global__ __launch_bounds__(512,2)
void gemm_fq(const ushort* __restrict__ A0, const ushort* __restrict__ A1,
             const ushort* __restrict__ Wh0, const ushort* __restrict__ Wl0,
             const ushort* __restrict__ Wh1, const ushort* __restrict__ Wl1,
             const float* __restrict__ b0, const float* __restrict__ b1,
             ushort* __restrict__ C0, ushort* __restrict__ C1)
{
    const int z = blockIdx.z;
    const ushort* A  = z ? A1 : A0;
    const ushort* Wh = z ? Wh1 : Wh0;
    const ushort* Wl = z ? Wl1 : Wl0;
    const float* bias = z ? b1 : b0;
    ushort* C = z ? C1 : C0;

    __shared__ ushort sA[128*168];       // full K=160 resident (pad 168)
    __shared__ ushort sW[2][480*40];     // k-chunk of 32 (pad 40), hi/lo planes

    const int tid = threadIdx.x;
    const int lane = tid & 63, wave = tid >> 6;
    const int wm = wave >> 1, wn = wave & 1;    // 4 x 2 wave grid
    const int ln = lane & 15, q = lane >> 4;
    const long m0 = (long)blockIdx.x * 128;

    // stage A (128 x 160 bf16): 2560 uint4
#pragma unroll
    for (int i=0;i<5;i++){
        int e = tid + 512*i;
        int m = e/20, s = e - m*20;
        *(uint4*)(sA + m*168 + s*8) = *(const uint4*)(A + (m0+m)*160 + s*8);
    }

    f32x4 acc[2][15];
#pragma unroll
    for (int mt=0;mt<2;mt++)
#pragma unroll
        for (int nt=0;nt<15;nt++)
#pragma unroll
            for (int r=0;r<4;r++) acc[mt][nt][r] = 0.f;

    for (int kc=0;kc<5;kc++){
        const int k0 = kc*32;
        __syncthreads();
        // stage W chunk: both planes, 480x32 each -> 3840 uint4
#pragma unroll
        for (int i=0;i<8;i++){
            int e = tid + 512*i;
            if (e < 3840){
                int pl = (e >= 1920);
                int ee = e - pl*1920;
                int n = ee >> 2, s = ee & 3;
                const ushort* src = (pl ? Wl : Wh) + (long)n*160 + k0 + s*8;
                *(uint4*)(sW[pl] + n*40 + s*8) = *(const uint4*)src;
            }
        }
        __syncthreads();

        bf16x8 af[2];
#pragma unroll
        for (int mt=0;mt<2;mt++)
            af[mt] = *(const bf16x8*)(sA + (wm*32 + mt*16 + ln)*168 + k0 + q*8);
#pragma unroll
        for (int nt=0;nt<15;nt++){
            int offw = (wn*240 + nt*16 + ln)*40 + q*8;
            bf16x8 bh = *(const bf16x8*)(sW[0] + offw);
            bf16x8 bl = *(const bf16x8*)(sW[1] + offw);
#pragma unroll
            for (int mt=0;mt<2;mt++){
                acc[mt][nt] = __builtin_amdgcn_mfma_f32_16x16x32_bf16(af[mt], bh, acc[mt][nt], 0,0,0);
                acc[mt][nt] = __builtin_amdgcn_mfma_f32_16x16x32_bf16(af[mt], bl, acc[mt][nt], 0,0,0);
            }
        }
    }

#pragma unroll
    for (int nt=0;nt<15;nt++){
        int col = wn*240 + nt*16 + ln;
        float bv = bias[col];
#pragma unroll
        for (int mt=0;mt<2;mt++){
#pragma unroll
            for (int r=0;r<4;r++){
                long row = m0 + wm*32 + mt*16 + q*4 + r;
                C[row*480 + col] = f2bf(acc[mt][nt][r] + bv);
            }
        }
    }
}

// ============================ O3 GEMM + fused max-pool ============
// A = O2 (M x 160 bf16), W = f_out_w (160x160 hi/lo, fully LDS-resident).
// Block tile 128M (= 4 nodes) x 160N; wave (wm 0..3 = node, wn 0..1): 32M x 80N.
// Epilogue: col-max over each node's 32 rows + f_out_b -> pooled (fp32).
__global__ __launch_bounds__(512,2)
void gemm_o3pool(const ushort* __restrict__ A,
                 const ushort* __restrict__ Wh, const ushort* __restrict__ Wl,
                 const float* __restrict__ fb, float* __restrict__ pooled,
                 int node_base)
{
    __shared__ ushort sA[128*168];
    __shared__ ushort sW[2][160*168];

    const int tid = threadIdx.x;
    const int lane = tid & 63, wave = tid >> 6;
    const int wm = wave >> 1, wn = wave & 1;
    const int ln = lane & 15, q = lane >> 4;
    const long m0 = (long)blockIdx.x * 128;

#pragma unroll
    for (int i=0;i<5;i++){
        int e = tid + 512*i;
        int m = e/20, s = e - m*20;
        *(uint4*)(sA + m*168 + s*8) = *(const uint4*)(A + (m0+m)*160 + s*8);
    }
#pragma unroll
    for (int i=0;i<13;i++){
        int e = tid + 512*i;
        if (e < 6400){
            int pl = (e >= 3200);
            int ee = e - pl*3200;
            int n = ee/20, s = ee - n*20;
            const ushort* src = (pl ? Wl : Wh) + n*160 + s*8;
            *(uint4*)(sW[pl] + n*168 + s*8) = *(const uint4*)src;
        }
    }
    __syncthreads();

    f32x4 acc[2][5];
#pragma unroll
    for (int mt=0;mt<2;mt++)
#pragma unroll
        for (int nt=0;nt<5;nt++)
#pragma unroll
            for (int r=0;r<4;r++) acc[mt][nt][r] = 0.f;

#pragma unroll
    for (int kc=0;kc<5;kc++){
        const int k0 = kc*32;
        bf16x8 af[2];
#pragma unroll
        for (int mt=0;mt<2;mt++)
            af[mt] = *(const bf16x8*)(sA + (wm*32 + mt*16 + ln)*168 + k0 + q*8);
#pragma unroll
        for (int nt=0;nt<5;nt++){
            int offw = (wn*80 + nt*16 + ln)*168 + k0 + q*8;
            bf16x8 bh = *(const bf16x8*)(sW[0] + offw);
            bf16x8 bl = *(const bf16x8*)(sW[1] + offw);
#pragma unroll
            for (int mt=0;mt<2;mt++){
                acc[mt][nt] = __builtin_amdgcn_mfma_f32_16x16x32_bf16(af[mt], bh, acc[mt][nt], 0,0,0);
                acc[mt][nt] = __builtin_amdgcn_mfma_f32_16x16x32_bf16(af[mt], bl, acc[mt][nt], 0,0,0);
            }
        }
    }

    // fused max-pool: wave wm covers exactly node (node_base + bx*4 + wm) rows
    const int node = node_base + blockIdx.x*4 + wm;
#pragma unroll
    for (int nt=0;nt<5;nt++){
        float m = acc[0][nt][0];
#pragma unroll
        for (int mt=0;mt<2;mt++)
#pragma unroll
            for (int r=0;r<4;r++) m = fmaxf(m, acc[mt][nt][r]);
        m = fmaxf(m, __shfl_xor(m, 16));
        m = fmaxf(m, __shfl_xor(m, 32));
        if (q == 0){
            int col = wn*80 + nt*16 + ln;
            pooled[(long)node*160 + col] = m + fb[col];
        }
    }
}

// ============================ per-node attention, layers 1/2 ============
__global__ __launch_bounds__(NTH)
void attn_layer(const float* __restrict__ XPi, const float* __restrict__ XPo,
                const int* __restrict__ in_idx, const int* __restrict__ out_idx,
                ushort* __restrict__ Oi, ushort* __restrict__ Oo, int node_base)
{
    const float* XP = blockIdx.y ? XPo : XPi;
    const int*  idx = blockIdx.y ? out_idx : in_idx;
    ushort* O       = blockIdx.y ? Oo : Oi;

    __shared__ float XPg[16*484];
    __shared__ float SS[80*17];
    __shared__ int sIdx[16];
    const int tid = threadIdx.x;
    const int nl  = blockIdx.x;
    const int node = node_base + nl;
    const int bb = node >> 12, nn = node & 4095;

    if (tid < 16) sIdx[tid] = (tid==0) ? nn : idx[(long)node*15 + tid-1];
    __syncthreads();
    for (int e=tid;e<1920;e+=NTH){
        int r = e/120, c4 = e - r*120;
        float4 v = *(const float4*)(XP + (long)(bb*4096 + sIdx[r])*480 + c4*4);
        *(float4*)(XPg + r*484 + c4*4) = v;
    }
    __syncthreads();
    for (int o=tid;o<1280;o+=NTH){
        int h=o>>8, ij=o&255, i=ij>>4, j=ij&15;
        const float* qp = XPg + i*484 + h*32;
        const float* kp = XPg + j*484 + 160 + h*32;
        float s = 0.f;
#pragma unroll
        for (int d=0;d<32;d++) s = fmaf(qp[d], kp[d], s);
        SS[(h*16+i)*17 + j] = s * 0.17677669529663687f;
    }
    __syncthreads();
    if (tid < 80){
        float* row = SS + tid*17;
        float m = row[0];
#pragma unroll
        for (int j=1;j<16;j++) m = fmaxf(m, row[j]);
        float sum=0.f, ev[16];
#pragma unroll
        for (int j=0;j<16;j++){ ev[j]=__expf(row[j]-m); sum+=ev[j]; }
        float inv = 1.f/sum;
#pragma unroll
        for (int j=0;j<16;j++) row[j] = ev[j]*inv;
    }
    __syncthreads();
    for (int o=tid;o<2560;o+=NTH){
        int r=o/160, c=o-r*160, h=c>>5;
        const float* srow = SS + (h*16+r)*17;
        const float* v = XPg + 320 + c;
        float s = 0.f;
#pragma unroll
        for (int j=0;j<16;j++) s = fmaf(srow[j], v[j*484], s);
        O[(long)(nl*16+r)*160 + c] = f2bf(s);
    }
}

// ============================ per-node final attention ============
__global__ __launch_bounds__(NTH)
void attn_final(const ushort* __restrict__ FQi, const ushort* __restrict__ FQo,
                ushort* __restrict__ O2)
{
    __shared__ float F[32*484];
    __shared__ float S2[32*33];
    const int tid = threadIdx.x;
    const int nl  = blockIdx.x;

    for (int e=tid;e<3840;e+=NTH){
        int r = e/120, c4 = e - r*120;
        const ushort* src = (r<16) ? (FQi + (long)(nl*16+r)*480 + c4*4)
                                   : (FQo + (long)(nl*16+r-16)*480 + c4*4);
        ushort4 u = *(const ushort4*)src;
        float* dst = F + r*484 + c4*4;
        dst[0]=bf2f(u.x); dst[1]=bf2f(u.y); dst[2]=bf2f(u.z); dst[3]=bf2f(u.w);
    }
    __syncthreads();
    for (int o=tid;o<1024;o+=NTH){
        int i=o>>5, j=o&31;
        const float* qp = F + i*484;
        const float* kp = F + j*484 + 160;
        float s = 0.f;
        for (int d=0;d<160;d++) s = fmaf(qp[d], kp[d], s);
        S2[i*33 + j] = s * 0.07905694150420949f;
    }
    __syncthreads();
    if (tid < 32){
        float* row = S2 + tid*33;
        float m = row[0];
#pragma unroll
        for (int j=1;j<32;j++) m = fmaxf(m, row[j]);
        float sum=0.f, ev[32];
#pragma unroll
        for (int j=0;j<32;j++){ ev[j]=__expf(row[j]-m); sum+=ev[j]; }
        float inv = 1.f/sum;
#pragma unroll
        for (int j=0;j<32;j++) row[j] = ev[j]*inv;
    }
    __syncthreads();
    for (int o=tid;o<5120;o+=NTH){
        int r=o/160, c=o-r*160;
        const float* srow = S2 + r*33;
        const float* v = F + 320 + c;
        float s = 0.f;
#pragma unroll
        for (int j=0;j<32;j++) s = fmaf(srow[j], v[j*484], s);
        O2[(long)(nl*32+r)*160 + c] = f2bf(s);
    }
}

// ============================ host ============================
extern "C" void kernel_launch(void* const* d_in, const int* in_sizes, int n_in,
                              void* d_out, int out_size, void* d_ws, size_t ws_size,
                              hipStream_t stream)
{
    const float* X       = (const float*)d_in[0];
    const int*   in_idx  = (const int*)  d_in[1];
    const int*   out_idx = (const int*)  d_in[2];
    const float* iWq     = (const float*)d_in[3];
    const float* iWk     = (const float*)d_in[4];
    const float* iWv     = (const float*)d_in[5];
    const float* i_in_w  = (const float*)d_in[6];
    const float* i_in_b  = (const float*)d_in[7];
    const float* i_out_w = (const float*)d_in[8];
    const float* i_out_b = (const float*)d_in[9];
    const float* oWq     = (const float*)d_in[10];
    const float* oWk     = (const float*)d_in[11];
    const float* oWv     = (const float*)d_in[12];
    const float* o_in_w  = (const float*)d_in[13];
    const float* o_in_b  = (const float*)d_in[14];
    const float* o_out_w = (const float*)d_in[15];
    const float* o_out_b = (const float*)d_in[16];
    const float* f_in_w  = (const float*)d_in[17];
    const float* f_in_b  = (const float*)d_in[18];
    const float* f_out_w = (const float*)d_in[19];
    const float* f_out_b = (const float*)d_in[20];
    const float* lin_w   = (const float*)d_in[21];
    const float* lin_b   = (const float*)d_in[22];

    float* ws = (float*)d_ws;
    float* XP_i   = ws;                          // 32768*480
    float* XP_o   = XP_i + 15728640;
    float* pooled = XP_o + 15728640;             // 32768*160
    float* c_i    = pooled + 5242880;
    float* c_o    = c_i + 480;
    ushort* ub = (ushort*)(c_o + 480);
    ushort* Wci_h = ub;
    ushort* Wci_l = Wci_h + 76800;
    ushort* Wco_h = Wci_l + 76800;
    ushort* Wco_l = Wco_h + 76800;
    ushort* Hi_h  = Wco_l + 76800;
    ushort* Hi_l  = Hi_h  + 76800;
    ushort* Ho_h  = Hi_l  + 76800;
    ushort* Ho_l  = Ho_h  + 76800;
    ushort* fo_h  = Ho_l  + 76800;
    ushort* fo_l  = fo_h  + 25600;
    ushort* li_h  = fo_l  + 25600;
    ushort* li_l  = li_h  + 25600;
    ushort* sb_us = li_l + 25600;
    const unsigned long long fixed = 36701760ULL;   // floats used by fixed region

    size_t avail = ws_size / 4;
    int ns = 4096;
    while (ns > 64 && fixed + 12800ULL*ns > avail) ns >>= 1;

    // slice buffers (all bf16)
    ushort* O_i = sb_us;                          // ns*16*160
    ushort* O_o = O_i + (size_t)2560*ns;
    ushort* FQi = O_o + (size_t)2560*ns;          // ns*16*480
    ushort* FQo = FQi + (size_t)7680*ns;
    ushort* O2  = FQo + (size_t)7680*ns;          // ns*32*160

    // prep
    prep_combined_bf<<<300,NTH,0,stream>>>(iWq,iWk,iWv,i_in_w, Wci_h, Wci_l);
    prep_combined_bf<<<300,NTH,0,stream>>>(oWq,oWk,oWv,o_in_w, Wco_h, Wco_l);
    prep_H_bf<<<300,NTH,0,stream>>>(f_in_w, i_out_w, Hi_h, Hi_l);
    prep_H_bf<<<300,NTH,0,stream>>>(f_in_w, o_out_w, Ho_h, Ho_l);
    prep_cvec<<<2,NTH,0,stream>>>(f_in_w, i_out_b, f_in_b, c_i);
    prep_cvec<<<2,NTH,0,stream>>>(f_in_w, o_out_b, f_in_b, c_o);
    prep_conv_bf<<<100,NTH,0,stream>>>(f_out_w, fo_h, fo_l, 25600);
    prep_conv_bf<<<100,NTH,0,stream>>>(lin_w,   li_h, li_l, 25600);

    // XP = X @ Wc^T + in_b  (fp32 out; both layers via z)
    dim3 g1(256, 3, 2);
    gemm_mfma<0><<<g1,NTH,0,stream>>>(X, X, Wci_h, Wci_l, Wco_h, Wco_l,
                                      i_in_b, o_in_b, XP_i, XP_o, 480);

    int S = 32768 / ns;
    for (int s=0;s<S;s++){
        int base = s*ns;
        dim3 ga(ns, 2);
        attn_layer<<<ga,NTH,0,stream>>>(XP_i, XP_o, in_idx, out_idx, O_i, O_o, base);
        dim3 g3(ns/8, 1, 2);
        gemm_fq<<<g3,512,0,stream>>>(O_i, O_o, Hi_h, Hi_l, Ho_h, Ho_l,
                                     c_i, c_o, FQi, FQo);
        attn_final<<<ns,NTH,0,stream>>>(FQi, FQo, O2);
        gemm_o3pool<<<ns/4,512,0,stream>>>(O2, fo_h, fo_l, f_out_b, pooled, base);
    }

    // out = ELU(pooled @ lin_w^T + lin_b)
    dim3 g6(256, 1, 1);
    gemm_mfma<1><<<g6,NTH,0,stream>>>(pooled, pooled, li_h, li_l, li_h, li_l,
                                      lin_b, lin_b, (float*)d_out, (float*)d_out, 160);
}

// Round 6
// 1641.009 us; speedup vs baseline: 15.3478x; 1.9527x over previous
//
#include <hip/hip_runtime.h>
#include <hip/hip_bf16.h>
#include <math.h>

#define NTH 256

typedef __bf16 bf16x8 __attribute__((ext_vector_type(8)));
typedef float  f32x4  __attribute__((ext_vector_type(4)));
typedef unsigned short ushort;
typedef ushort u16x8 __attribute__((ext_vector_type(8)));

__device__ __forceinline__ ushort f2bf(float x){
    union { float f; unsigned int u; } v; v.f = x;
    unsigned int r = v.u + 0x7fffu + ((v.u >> 16) & 1u);
    return (ushort)(r >> 16);
}
__device__ __forceinline__ float bf2f(ushort h){
    union { unsigned int u; float f; } v; v.u = ((unsigned int)h) << 16;
    return v.f;
}

// ============================ prep kernels ============================
__global__ void prep_combined_bf(const float* __restrict__ Wq, const float* __restrict__ Wk,
                                 const float* __restrict__ Wv, const float* __restrict__ in_w,
                                 ushort* __restrict__ dh, ushort* __restrict__ dl)
{
    int o = blockIdx.x*NTH + threadIdx.x;
    if (o >= 76800) return;
    int c = o/160, j = o - c*160;
    const float* Wsel = (c<160) ? Wq : (c<320) ? Wk : Wv;
    const float* wrow = Wsel + j*160;
    const float* irow = in_w + c*160;
    float s = 0.f;
    for (int k=0;k<160;k++) s = fmaf(wrow[k], irow[k], s);
    ushort h = f2bf(s);
    dh[o] = h; dl[o] = f2bf(s - bf2f(h));
}

__global__ void prep_H_bf(const float* __restrict__ f_in_w, const float* __restrict__ out_w,
                          ushort* __restrict__ dh, ushort* __restrict__ dl)
{
    int o = blockIdx.x*NTH + threadIdx.x;
    if (o >= 76800) return;
    int n = o/160, k = o - n*160;
    float s = 0.f;
    for (int c=0;c<160;c++) s = fmaf(f_in_w[n*160+c], out_w[c*160+k], s);
    ushort h = f2bf(s);
    dh[o] = h; dl[o] = f2bf(s - bf2f(h));
}

__global__ void prep_cvec(const float* __restrict__ f_in_w, const float* __restrict__ out_b,
                          const float* __restrict__ f_in_b, float* __restrict__ cv)
{
    int n = blockIdx.x*NTH + threadIdx.x;
    if (n >= 480) return;
    float s = f_in_b[n];
    for (int c=0;c<160;c++) s = fmaf(f_in_w[n*160+c], out_b[c], s);
    cv[n] = s;
}

__global__ void prep_conv_bf(const float* __restrict__ src,
                             ushort* __restrict__ dh, ushort* __restrict__ dl, int n)
{
    int o = blockIdx.x*NTH + threadIdx.x;
    if (o >= n) return;
    float s = src[o];
    ushort h = f2bf(s);
    dh[o] = h; dl[o] = f2bf(s - bf2f(h));
}

// ============================ MFMA GEMM (fp32 A, split x3) ============
// C(M x N) = A(M x 160) @ W(N x 160)^T + bias. EPI 1: fp32 +bias+ELU; EPI 2: bf16 +bias.
template<int EPI>
__global__ __launch_bounds__(NTH)
void gemm_mfma(const float* __restrict__ A0, const float* __restrict__ A1,
               const ushort* __restrict__ Wh0, const ushort* __restrict__ Wl0,
               const ushort* __restrict__ Wh1, const ushort* __restrict__ Wl1,
               const float* __restrict__ b0, const float* __restrict__ b1,
               void* C0v, void* C1v, int N)
{
    const int z = blockIdx.z;
    const float* A = z ? A1 : A0;
    const ushort* Wh = z ? Wh1 : Wh0;
    const ushort* Wl = z ? Wl1 : Wl0;
    const float* bias = z ? b1 : b0;

    __shared__ ushort sAh[128*40], sAl[128*40];
    __shared__ ushort sWh[160*40], sWl[160*40];

    const int tid = threadIdx.x;
    const int lane = tid & 63, wave = tid >> 6;
    const int wm = wave >> 1, wn = wave & 1;
    const int ln = lane & 15, g = lane >> 4;
    const long m0 = (long)blockIdx.x * 128;
    const int  n0 = blockIdx.y * 160;

    f32x4 acc[4][5];
#pragma unroll
    for (int mt=0;mt<4;mt++)
#pragma unroll
        for (int nt=0;nt<5;nt++)
#pragma unroll
            for (int r=0;r<4;r++) acc[mt][nt][r] = 0.f;

    for (int k0=0;k0<160;k0+=32){
#pragma unroll
        for (int i=0;i<4;i++){
            int f = tid + 256*i;
            int m = f >> 3, seg = f & 7;
            float4 v = *(const float4*)(A + (m0+m)*160 + k0 + seg*4);
            ushort4 hv, lv;
            hv.x = f2bf(v.x); lv.x = f2bf(v.x - bf2f(hv.x));
            hv.y = f2bf(v.y); lv.y = f2bf(v.y - bf2f(hv.y));
            hv.z = f2bf(v.z); lv.z = f2bf(v.z - bf2f(hv.z));
            hv.w = f2bf(v.w); lv.w = f2bf(v.w - bf2f(hv.w));
            *(ushort4*)(sAh + m*40 + seg*4) = hv;
            *(ushort4*)(sAl + m*40 + seg*4) = lv;
        }
#pragma unroll
        for (int i=0;i<5;i++){
            int e = tid + 256*i;
            int pl = (e >= 640);
            int idx = pl ? e-640 : e;
            int n = idx >> 2, seg = idx & 3;
            const ushort* src = (pl ? Wl : Wh) + (long)(n0+n)*160 + k0 + seg*8;
            ushort* dst = (pl ? sWl : sWh) + n*40 + seg*8;
            *(uint4*)dst = *(const uint4*)src;
        }
        __syncthreads();

        bf16x8 ah[4], al[4];
#pragma unroll
        for (int mt=0;mt<4;mt++){
            int off = (wm*64 + mt*16 + ln)*40 + g*8;
            ah[mt] = *(const bf16x8*)(sAh + off);
            al[mt] = *(const bf16x8*)(sAl + off);
        }
#pragma unroll
        for (int nt=0;nt<5;nt++){
            int offw = (wn*80 + nt*16 + ln)*40 + g*8;
            bf16x8 bh = *(const bf16x8*)(sWh + offw);
            bf16x8 bl = *(const bf16x8*)(sWl + offw);
#pragma unroll
            for (int mt=0;mt<4;mt++){
                acc[mt][nt] = __builtin_amdgcn_mfma_f32_16x16x32_bf16(ah[mt], bh, acc[mt][nt], 0,0,0);
                acc[mt][nt] = __builtin_amdgcn_mfma_f32_16x16x32_bf16(ah[mt], bl, acc[mt][nt], 0,0,0);
                acc[mt][nt] = __builtin_amdgcn_mfma_f32_16x16x32_bf16(al[mt], bh, acc[mt][nt], 0,0,0);
            }
        }
        __syncthreads();
    }

#pragma unroll
    for (int nt=0;nt<5;nt++){
        int col = n0 + wn*80 + nt*16 + ln;
        float bv = bias[col];
#pragma unroll
        for (int mt=0;mt<4;mt++){
#pragma unroll
            for (int r=0;r<4;r++){
                long row = m0 + wm*64 + mt*16 + g*4 + r;
                float x = acc[mt][nt][r] + bv;
                if (EPI==1){
                    x = x > 0.f ? x : expm1f(x);
                    ((float*)(z ? C1v : C0v))[row*N + col] = x;
                } else {
                    ((ushort*)(z ? C1v : C0v))[row*N + col] = f2bf(x);
                }
            }
        }
    }
}

// ============================ FQ GEMM: A bf16 resident, W streamed ============
__global__ __launch_bounds__(512,2)
void gemm_fq(const ushort* __restrict__ A0, const ushort* __restrict__ A1,
             const ushort* __restrict__ Wh0, const ushort* __restrict__ Wl0,
             const ushort* __restrict__ Wh1, const ushort* __restrict__ Wl1,
             const float* __restrict__ b0, const float* __restrict__ b1,
             ushort* __restrict__ C0, ushort* __restrict__ C1)
{
    const int z = blockIdx.z;
    const ushort* A  = z ? A1 : A0;
    const ushort* Wh = z ? Wh1 : Wh0;
    const ushort* Wl = z ? Wl1 : Wl0;
    const float* bias = z ? b1 : b0;
    ushort* C = z ? C1 : C0;

    __shared__ ushort sA[128*168];
    __shared__ ushort sW[2][480*40];

    const int tid = threadIdx.x;
    const int lane = tid & 63, wave = tid >> 6;
    const int wm = wave >> 1, wn = wave & 1;
    const int ln = lane & 15, q = lane >> 4;
    const long m0 = (long)blockIdx.x * 128;

#pragma unroll
    for (int i=0;i<5;i++){
        int e = tid + 512*i;
        int m = e/20, s = e - m*20;
        *(uint4*)(sA + m*168 + s*8) = *(const uint4*)(A + (m0+m)*160 + s*8);
    }

    f32x4 acc[2][15];
#pragma unroll
    for (int mt=0;mt<2;mt++)
#pragma unroll
        for (int nt=0;nt<15;nt++)
#pragma unroll
            for (int r=0;r<4;r++) acc[mt][nt][r] = 0.f;

    for (int kc=0;kc<5;kc++){
        const int k0 = kc*32;
        __syncthreads();
#pragma unroll
        for (int i=0;i<8;i++){
            int e = tid + 512*i;
            if (e < 3840){
                int pl = (e >= 1920);
                int ee = e - pl*1920;
                int n = ee >> 2, s = ee & 3;
                const ushort* src = (pl ? Wl : Wh) + (long)n*160 + k0 + s*8;
                *(uint4*)(sW[pl] + n*40 + s*8) = *(const uint4*)src;
            }
        }
        __syncthreads();

        bf16x8 af[2];
#pragma unroll
        for (int mt=0;mt<2;mt++)
            af[mt] = *(const bf16x8*)(sA + (wm*32 + mt*16 + ln)*168 + k0 + q*8);
#pragma unroll
        for (int nt=0;nt<15;nt++){
            int offw = (wn*240 + nt*16 + ln)*40 + q*8;
            bf16x8 bh = *(const bf16x8*)(sW[0] + offw);
            bf16x8 bl = *(const bf16x8*)(sW[1] + offw);
#pragma unroll
            for (int mt=0;mt<2;mt++){
                acc[mt][nt] = __builtin_amdgcn_mfma_f32_16x16x32_bf16(af[mt], bh, acc[mt][nt], 0,0,0);
                acc[mt][nt] = __builtin_amdgcn_mfma_f32_16x16x32_bf16(af[mt], bl, acc[mt][nt], 0,0,0);
            }
        }
    }

#pragma unroll
    for (int nt=0;nt<15;nt++){
        int col = wn*240 + nt*16 + ln;
        float bv = bias[col];
#pragma unroll
        for (int mt=0;mt<2;mt++){
#pragma unroll
            for (int r=0;r<4;r++){
                long row = m0 + wm*32 + mt*16 + q*4 + r;
                C[row*480 + col] = f2bf(acc[mt][nt][r] + bv);
            }
        }
    }
}

// ============================ MFMA attention, layers 1/2 ============
// One wave (64thr) per node. XP bf16 [q|k|v] 480 cols. S^T=K@Q^T so softmaxed
// C-frag feeds PV as A-operand (K=32 mfma, j=0..15 real via quads 0,1).
__global__ __launch_bounds__(64)
void attn_layer_mfma(const ushort* __restrict__ XPi, const ushort* __restrict__ XPo,
                     const int* __restrict__ in_idx, const int* __restrict__ out_idx,
                     ushort* __restrict__ Oi, ushort* __restrict__ Oo, int node_base)
{
    const ushort* XP = blockIdx.y ? XPo : XPi;
    const int*  idx  = blockIdx.y ? out_idx : in_idx;
    ushort* O        = blockIdx.y ? Oo : Oi;

    __shared__ ushort XPg[16*496];      // stride 496 (16B-aligned, banks spread)
    __shared__ ushort Pall[5*16*24];    // per-head 16x16 P, stride 24

    const int lane = threadIdx.x;
    const int ln = lane & 15, q = lane >> 4;
    const int node = node_base + blockIdx.x;
    const int bb = node >> 12, nn = node & 4095;

    int idxv = nn;
    if (lane >= 1 && lane < 16) idxv = idx[(long)node*15 + lane-1];

    // gather 16 rows x 480 ushorts (960 uint4, 15/lane)
#pragma unroll
    for (int i=0;i<15;i++){
        int e = lane + 64*i;
        int r = e/60, c = e - r*60;
        int rowg = __shfl(idxv, r);
        *(uint4*)(XPg + r*496 + c*8) =
            *(const uint4*)(XP + (long)(bb*4096 + rowg)*480 + c*8);
    }
    __syncthreads();

    const float scale = 0.17677669529663687f;   // 1/sqrt(32)
#pragma unroll
    for (int h=0;h<5;h++){
        // S^T = K_h @ Q_h^T  (A=K: lane row ln; B=Q: lane row ln)
        bf16x8 ka = *(const bf16x8*)(XPg + ln*496 + 160 + h*32 + q*8);
        bf16x8 qb = *(const bf16x8*)(XPg + ln*496 +       h*32 + q*8);
        f32x4 s = {0.f,0.f,0.f,0.f};
        s = __builtin_amdgcn_mfma_f32_16x16x32_bf16(ka, qb, s, 0,0,0);
        float x[4], m = -1e30f;
#pragma unroll
        for (int r=0;r<4;r++){ x[r] = s[r]*scale; m = fmaxf(m, x[r]); }
        m = fmaxf(m, __shfl_xor(m, 16));
        m = fmaxf(m, __shfl_xor(m, 32));
        float e0[4], sum = 0.f;
#pragma unroll
        for (int r=0;r<4;r++){ e0[r] = __expf(x[r]-m); sum += e0[r]; }
        sum += __shfl_xor(sum, 16);
        sum += __shfl_xor(sum, 32);
        float inv = 1.f/sum;
        ushort4 pw;
        pw.x = f2bf(e0[0]*inv); pw.y = f2bf(e0[1]*inv);
        pw.z = f2bf(e0[2]*inv); pw.w = f2bf(e0[3]*inv);
        // lane holds P[i=ln][j=q*4+r] -> write row ln, cols q*4..q*4+3
        *(ushort4*)(Pall + h*384 + ln*24 + q*4) = pw;
    }
    __syncthreads();

#pragma unroll
    for (int h=0;h<5;h++){
        // A-frag: P[ln][k=q*8+jj], quads 2,3 zero (j only 0..15)
        u16x8 ta;
#pragma unroll
        for (int jj=0;jj<8;jj++) ta[jj] = 0;
        if (q < 2) ta = *(const u16x8*)(Pall + h*384 + ln*24 + q*8);
        bf16x8 ap = *(bf16x8*)&ta;
#pragma unroll
        for (int half=0; half<2; half++){
            u16x8 tb;
#pragma unroll
            for (int jj=0;jj<8;jj++) tb[jj] = 0;
            if (q < 2){
#pragma unroll
                for (int jj=0;jj<8;jj++)
                    tb[jj] = XPg[(q*8+jj)*496 + 320 + h*32 + half*16 + ln];
            }
            bf16x8 bv = *(bf16x8*)&tb;
            f32x4 o = {0.f,0.f,0.f,0.f};
            o = __builtin_amdgcn_mfma_f32_16x16x32_bf16(ap, bv, o, 0,0,0);
#pragma unroll
            for (int r=0;r<4;r++)
                O[(long)(blockIdx.x*16 + q*4 + r)*160 + h*32 + half*16 + ln] = f2bf(o[r]);
        }
    }
}

// ============================ MFMA final attention ============
// One wave per node. F rows 0-15 from FQi, 16-31 from FQo (480 = [fq|fk|fv]).
// Phase1: stage fq|fk (320), scores via 2x2x5 MFMA, softmax, P->LDS.
// Phase2: stage fv (stride 168, reuse), PV via K=32 MFMA, write O2 bf16.
__global__ __launch_bounds__(64)
void attn_final_mfma(const ushort* __restrict__ FQi, const ushort* __restrict__ FQo,
                     ushort* __restrict__ O2)
{
    __shared__ ushort F[32*328];
    __shared__ ushort P[32*40];

    const int lane = threadIdx.x;
    const int ln = lane & 15, q = lane >> 4;
    const int nl = blockIdx.x;

#pragma unroll
    for (int i=0;i<20;i++){
        int e = lane + 64*i;
        int r = e/40, c = e - r*40;
        const ushort* src = (r<16) ? (FQi + (long)(nl*16+r)*480 + c*8)
                                   : (FQo + (long)(nl*16+r-16)*480 + c*8);
        *(uint4*)(F + r*328 + c*8) = *(const uint4*)src;
    }
    __syncthreads();

    // S2^T[tj][ti] tiles, K=160
    f32x4 sc[2][2];
#pragma unroll
    for (int ti=0;ti<2;ti++)
#pragma unroll
        for (int tj=0;tj<2;tj++){
            f32x4 a = {0.f,0.f,0.f,0.f};
#pragma unroll
            for (int kc=0;kc<5;kc++){
                bf16x8 ka = *(const bf16x8*)(F + (tj*16+ln)*328 + 160 + kc*32 + q*8);
                bf16x8 qb = *(const bf16x8*)(F + (ti*16+ln)*328 +       kc*32 + q*8);
                a = __builtin_amdgcn_mfma_f32_16x16x32_bf16(ka, qb, a, 0,0,0);
            }
            sc[ti][tj] = a;
        }

    const float scale = 0.07905694150420949f;   // 1/sqrt(160)
#pragma unroll
    for (int ti=0;ti<2;ti++){
        float x[2][4], m = -1e30f;
#pragma unroll
        for (int tj=0;tj<2;tj++)
#pragma unroll
            for (int r=0;r<4;r++){ x[tj][r] = sc[ti][tj][r]*scale; m = fmaxf(m, x[tj][r]); }
        m = fmaxf(m, __shfl_xor(m, 16));
        m = fmaxf(m, __shfl_xor(m, 32));
        float sum = 0.f;
#pragma unroll
        for (int tj=0;tj<2;tj++)
#pragma unroll
            for (int r=0;r<4;r++){ x[tj][r] = __expf(x[tj][r]-m); sum += x[tj][r]; }
        sum += __shfl_xor(sum, 16);
        sum += __shfl_xor(sum, 32);
        float inv = 1.f/sum;
#pragma unroll
        for (int tj=0;tj<2;tj++){
            ushort4 pw;
            pw.x = f2bf(x[tj][0]*inv); pw.y = f2bf(x[tj][1]*inv);
            pw.z = f2bf(x[tj][2]*inv); pw.w = f2bf(x[tj][3]*inv);
            *(ushort4*)(P + (ti*16+ln)*40 + tj*16 + q*4) = pw;
        }
    }
    __syncthreads();

    // phase 2: stage Fv (32 x 160, stride 168) into F (reuse)
#pragma unroll
    for (int i=0;i<10;i++){
        int e = lane + 64*i;
        int r = e/20, c = e - r*20;
        const ushort* src = (r<16) ? (FQi + (long)(nl*16+r)*480 + 320 + c*8)
                                   : (FQo + (long)(nl*16+r-16)*480 + 320 + c*8);
        *(uint4*)(F + r*168 + c*8) = *(const uint4*)src;
    }
    __syncthreads();

    bf16x8 ap[2];
#pragma unroll
    for (int mi=0;mi<2;mi++)
        ap[mi] = *(const bf16x8*)(P + (mi*16+ln)*40 + q*8);   // k=q*8..q*8+7, all 32 real
#pragma unroll
    for (int nt=0;nt<10;nt++){
        u16x8 tb;
#pragma unroll
        for (int jj=0;jj<8;jj++) tb[jj] = F[(q*8+jj)*168 + nt*16 + ln];
        bf16x8 bv = *(bf16x8*)&tb;
#pragma unroll
        for (int mi=0;mi<2;mi++){
            f32x4 o = {0.f,0.f,0.f,0.f};
            o = __builtin_amdgcn_mfma_f32_16x16x32_bf16(ap[mi], bv, o, 0,0,0);
#pragma unroll
            for (int r=0;r<4;r++)
                O2[(long)(nl*32 + mi*16 + q*4 + r)*160 + nt*16 + ln] = f2bf(o[r]);
        }
    }
}

// ============================ O3 GEMM + fused max-pool (k-chunked W) ============
__global__ __launch_bounds__(512)
void gemm_o3pool(const ushort* __restrict__ A,
                 const ushort* __restrict__ Wh, const ushort* __restrict__ Wl,
                 const float* __restrict__ fb, float* __restrict__ pooled,
                 int node_base)
{
    __shared__ ushort sA[128*168];
    __shared__ ushort sW[2][160*40];

    const int tid = threadIdx.x;
    const int lane = tid & 63, wave = tid >> 6;
    const int wm = wave >> 1, wn = wave & 1;
    const int ln = lane & 15, q = lane >> 4;
    const long m0 = (long)blockIdx.x * 128;

#pragma unroll
    for (int i=0;i<5;i++){
        int e = tid + 512*i;
        int m = e/20, s = e - m*20;
        *(uint4*)(sA + m*168 + s*8) = *(const uint4*)(A + (m0+m)*160 + s*8);
    }

    f32x4 acc[2][5];
#pragma unroll
    for (int mt=0;mt<2;mt++)
#pragma unroll
        for (int nt=0;nt<5;nt++)
#pragma unroll
            for (int r=0;r<4;r++) acc[mt][nt][r] = 0.f;

    for (int kc=0;kc<5;kc++){
        const int k0 = kc*32;
        __syncthreads();
#pragma unroll
        for (int i=0;i<3;i++){
            int e = tid + 512*i;
            if (e < 1280){
                int pl = (e >= 640);
                int ee = e - pl*640;
                int n = ee >> 2, s = ee & 3;
                *(uint4*)(sW[pl] + n*40 + s*8) =
                    *(const uint4*)((pl ? Wl : Wh) + n*160 + k0 + s*8);
            }
        }
        __syncthreads();

        bf16x8 af[2];
#pragma unroll
        for (int mt=0;mt<2;mt++)
            af[mt] = *(const bf16x8*)(sA + (wm*32 + mt*16 + ln)*168 + k0 + q*8);
#pragma unroll
        for (int nt=0;nt<5;nt++){
            int offw = (wn*80 + nt*16 + ln)*40 + q*8;
            bf16x8 bh = *(const bf16x8*)(sW[0] + offw);
            bf16x8 bl = *(const bf16x8*)(sW[1] + offw);
#pragma unroll
            for (int mt=0;mt<2;mt++){
                acc[mt][nt] = __builtin_amdgcn_mfma_f32_16x16x32_bf16(af[mt], bh, acc[mt][nt], 0,0,0);
                acc[mt][nt] = __builtin_amdgcn_mfma_f32_16x16x32_bf16(af[mt], bl, acc[mt][nt], 0,0,0);
            }
        }
    }

    const int node = node_base + blockIdx.x*4 + wm;
#pragma unroll
    for (int nt=0;nt<5;nt++){
        float m = acc[0][nt][0];
#pragma unroll
        for (int mt=0;mt<2;mt++)
#pragma unroll
            for (int r=0;r<4;r++) m = fmaxf(m, acc[mt][nt][r]);
        m = fmaxf(m, __shfl_xor(m, 16));
        m = fmaxf(m, __shfl_xor(m, 32));
        if (q == 0){
            int col = wn*80 + nt*16 + ln;
            pooled[(long)node*160 + col] = m + fb[col];
        }
    }
}

// ============================ host ============================
extern "C" void kernel_launch(void* const* d_in, const int* in_sizes, int n_in,
                              void* d_out, int out_size, void* d_ws, size_t ws_size,
                              hipStream_t stream)
{
    const float* X       = (const float*)d_in[0];
    const int*   in_idx  = (const int*)  d_in[1];
    const int*   out_idx = (const int*)  d_in[2];
    const float* iWq     = (const float*)d_in[3];
    const float* iWk     = (const float*)d_in[4];
    const float* iWv     = (const float*)d_in[5];
    const float* i_in_w  = (const float*)d_in[6];
    const float* i_in_b  = (const float*)d_in[7];
    const float* i_out_w = (const float*)d_in[8];
    const float* i_out_b = (const float*)d_in[9];
    const float* oWq     = (const float*)d_in[10];
    const float* oWk     = (const float*)d_in[11];
    const float* oWv     = (const float*)d_in[12];
    const float* o_in_w  = (const float*)d_in[13];
    const float* o_in_b  = (const float*)d_in[14];
    const float* o_out_w = (const float*)d_in[15];
    const float* o_out_b = (const float*)d_in[16];
    const float* f_in_w  = (const float*)d_in[17];
    const float* f_in_b  = (const float*)d_in[18];
    const float* f_out_w = (const float*)d_in[19];
    const float* f_out_b = (const float*)d_in[20];
    const float* lin_w   = (const float*)d_in[21];
    const float* lin_b   = (const float*)d_in[22];

    float* ws = (float*)d_ws;
    float* pooled = ws;                           // 32768*160 fp32
    float* c_i    = pooled + 5242880;             // 480
    float* c_o    = c_i + 480;
    ushort* ub    = (ushort*)(c_o + 480);
    ushort* XPb_i = ub;                           // 32768*480 bf16
    ushort* XPb_o = XPb_i + 15728640;
    ushort* Wci_h = XPb_o + 15728640;             // 76800 each
    ushort* Wci_l = Wci_h + 76800;
    ushort* Wco_h = Wci_l + 76800;
    ushort* Wco_l = Wco_h + 76800;
    ushort* Hi_h  = Wco_l + 76800;
    ushort* Hi_l  = Hi_h  + 76800;
    ushort* Ho_h  = Hi_l  + 76800;
    ushort* Ho_l  = Ho_h  + 76800;
    ushort* fo_h  = Ho_l  + 76800;                // 25600 each
    ushort* fo_l  = fo_h  + 25600;
    ushort* li_h  = fo_l  + 25600;
    ushort* li_l  = li_h  + 25600;
    ushort* sb_us = li_l + 25600;
    const unsigned long long fixed = 21330880ULL;   // floats

    size_t avail = ws_size / 4;
    int ns = 4096;
    while (ns > 64 && fixed + 12800ULL*ns > avail) ns >>= 1;

    ushort* O_i = sb_us;                          // ns*16*160
    ushort* O_o = O_i + (size_t)2560*ns;
    ushort* FQi = O_o + (size_t)2560*ns;          // ns*16*480
    ushort* FQo = FQi + (size_t)7680*ns;
    ushort* O2  = FQo + (size_t)7680*ns;          // ns*32*160

    prep_combined_bf<<<300,NTH,0,stream>>>(iWq,iWk,iWv,i_in_w, Wci_h, Wci_l);
    prep_combined_bf<<<300,NTH,0,stream>>>(oWq,oWk,oWv,o_in_w, Wco_h, Wco_l);
    prep_H_bf<<<300,NTH,0,stream>>>(f_in_w, i_out_w, Hi_h, Hi_l);
    prep_H_bf<<<300,NTH,0,stream>>>(f_in_w, o_out_w, Ho_h, Ho_l);
    prep_cvec<<<2,NTH,0,stream>>>(f_in_w, i_out_b, f_in_b, c_i);
    prep_cvec<<<2,NTH,0,stream>>>(f_in_w, o_out_b, f_in_b, c_o);
    prep_conv_bf<<<100,NTH,0,stream>>>(f_out_w, fo_h, fo_l, 25600);
    prep_conv_bf<<<100,NTH,0,stream>>>(lin_w,   li_h, li_l, 25600);

    // XP = X @ Wc^T + in_b  -> bf16 (both layers via z)
    dim3 g1(256, 3, 2);
    gemm_mfma<2><<<g1,NTH,0,stream>>>(X, X, Wci_h, Wci_l, Wco_h, Wco_l,
                                      i_in_b, o_in_b, XPb_i, XPb_o, 480);

    int S = 32768 / ns;
    for (int s=0;s<S;s++){
        int base = s*ns;
        dim3 ga(ns, 2);
        attn_layer_mfma<<<ga,64,0,stream>>>(XPb_i, XPb_o, in_idx, out_idx, O_i, O_o, base);
        dim3 g3(ns/8, 1, 2);
        gemm_fq<<<g3,512,0,stream>>>(O_i, O_o, Hi_h, Hi_l, Ho_h, Ho_l,
                                     c_i, c_o, FQi, FQo);
        attn_final_mfma<<<ns,64,0,stream>>>(FQi, FQo, O2);
        gemm_o3pool<<<ns/4,512,0,stream>>>(O2, fo_h, fo_l, f_out_b, pooled, base);
    }

    // out = ELU(pooled @ lin_w^T + lin_b)  fp32
    dim3 g6(256, 1, 1);
    gemm_mfma<1><<<g6,NTH,0,stream>>>(pooled, pooled, li_h, li_l, li_h, li_l,
                                      lin_b, lin_b, d_out, d_out, 160);
}

// Round 8
// 1410.104 us; speedup vs baseline: 17.8610x; 1.1638x over previous
//
#include <hip/hip_runtime.h>
#include <hip/hip_bf16.h>
#include <math.h>

#define NTH 256

typedef __bf16 bf16x8 __attribute__((ext_vector_type(8)));
typedef float  f32x4  __attribute__((ext_vector_type(4)));
typedef unsigned short ushort;
typedef ushort u16x8 __attribute__((ext_vector_type(8)));

__device__ __forceinline__ ushort f2bf(float x){
    union { float f; unsigned int u; } v; v.f = x;
    unsigned int r = v.u + 0x7fffu + ((v.u >> 16) & 1u);
    return (ushort)(r >> 16);
}
__device__ __forceinline__ float bf2f(ushort h){
    union { unsigned int u; float f; } v; v.u = ((unsigned int)h) << 16;
    return v.f;
}

// ============================ prep kernels ============================
__global__ void prep_combined_bf(const float* __restrict__ Wq, const float* __restrict__ Wk,
                                 const float* __restrict__ Wv, const float* __restrict__ in_w,
                                 ushort* __restrict__ dh)
{
    int o = blockIdx.x*NTH + threadIdx.x;
    if (o >= 76800) return;
    int c = o/160, j = o - c*160;
    const float* Wsel = (c<160) ? Wq : (c<320) ? Wk : Wv;
    const float* wrow = Wsel + j*160;
    const float* irow = in_w + c*160;
    float s = 0.f;
    for (int k=0;k<160;k++) s = fmaf(wrow[k], irow[k], s);
    dh[o] = f2bf(s);
}

__global__ void prep_H_bf(const float* __restrict__ f_in_w, const float* __restrict__ out_w,
                          ushort* __restrict__ dh)
{
    int o = blockIdx.x*NTH + threadIdx.x;
    if (o >= 76800) return;
    int n = o/160, k = o - n*160;
    float s = 0.f;
    for (int c=0;c<160;c++) s = fmaf(f_in_w[n*160+c], out_w[c*160+k], s);
    dh[o] = f2bf(s);
}

__global__ void prep_cvec(const float* __restrict__ f_in_w, const float* __restrict__ out_b,
                          const float* __restrict__ f_in_b, float* __restrict__ cv)
{
    int n = blockIdx.x*NTH + threadIdx.x;
    if (n >= 480) return;
    float s = f_in_b[n];
    for (int c=0;c<160;c++) s = fmaf(f_in_w[n*160+c], out_b[c], s);
    cv[n] = s;
}

__global__ void prep_conv_bf1(const float* __restrict__ src, ushort* __restrict__ dh, int n)
{
    int o = blockIdx.x*NTH + threadIdx.x;
    if (o >= n) return;
    dh[o] = f2bf(src[o]);
}

__global__ void prep_conv_bf2(const float* __restrict__ src,
                              ushort* __restrict__ dh, ushort* __restrict__ dl, int n)
{
    int o = blockIdx.x*NTH + threadIdx.x;
    if (o >= n) return;
    float s = src[o];
    ushort h = f2bf(s);
    dh[o] = h; dl[o] = f2bf(s - bf2f(h));
}

// ============================ MFMA GEMM (fp32 A) ============
// C(M x N) = A(M x 160) @ W(N x 160)^T + bias.
// SPLIT=2: ah*bh + al*bh (W hi only). SPLIT=3: + ah*bl.
// EPI 1: fp32 +bias+ELU; EPI 2: bf16 +bias.
template<int EPI, int SPLIT>
__global__ __launch_bounds__(NTH)
void gemm_mfma(const float* __restrict__ A0, const float* __restrict__ A1,
               const ushort* __restrict__ Wh0, const ushort* __restrict__ Wl0,
               const ushort* __restrict__ Wh1, const ushort* __restrict__ Wl1,
               const float* __restrict__ b0, const float* __restrict__ b1,
               void* C0v, void* C1v, int N)
{
    const int z = blockIdx.z;
    const float* A = z ? A1 : A0;
    const ushort* Wh = z ? Wh1 : Wh0;
    const ushort* Wl = z ? Wl1 : Wl0;
    const float* bias = z ? b1 : b0;

    __shared__ ushort sAh[128*40], sAl[128*40];
    __shared__ ushort sWh[160*40];
    __shared__ ushort sWl[(SPLIT==3) ? 160*40 : 8];

    const int tid = threadIdx.x;
    const int lane = tid & 63, wave = tid >> 6;
    const int wm = wave >> 1, wn = wave & 1;
    const int ln = lane & 15, g = lane >> 4;
    const long m0 = (long)blockIdx.x * 128;
    const int  n0 = blockIdx.y * 160;

    f32x4 acc[4][5];
#pragma unroll
    for (int mt=0;mt<4;mt++)
#pragma unroll
        for (int nt=0;nt<5;nt++)
#pragma unroll
            for (int r=0;r<4;r++) acc[mt][nt][r] = 0.f;

    for (int k0=0;k0<160;k0+=32){
#pragma unroll
        for (int i=0;i<4;i++){
            int f = tid + 256*i;
            int m = f >> 3, seg = f & 7;
            float4 v = *(const float4*)(A + (m0+m)*160 + k0 + seg*4);
            ushort4 hv, lv;
            hv.x = f2bf(v.x); lv.x = f2bf(v.x - bf2f(hv.x));
            hv.y = f2bf(v.y); lv.y = f2bf(v.y - bf2f(hv.y));
            hv.z = f2bf(v.z); lv.z = f2bf(v.z - bf2f(hv.z));
            hv.w = f2bf(v.w); lv.w = f2bf(v.w - bf2f(hv.w));
            *(ushort4*)(sAh + m*40 + seg*4) = hv;
            *(ushort4*)(sAl + m*40 + seg*4) = lv;
        }
        if (SPLIT == 3){
#pragma unroll
            for (int i=0;i<5;i++){
                int e = tid + 256*i;
                int pl = (e >= 640);
                int idx = pl ? e-640 : e;
                int n = idx >> 2, seg = idx & 3;
                const ushort* src = (pl ? Wl : Wh) + (long)(n0+n)*160 + k0 + seg*8;
                ushort* dst = (pl ? sWl : sWh) + n*40 + seg*8;
                *(uint4*)dst = *(const uint4*)src;
            }
        } else {
#pragma unroll
            for (int i=0;i<3;i++){
                int e = tid + 256*i;
                if (e < 640){
                    int n = e >> 2, seg = e & 3;
                    *(uint4*)(sWh + n*40 + seg*8) =
                        *(const uint4*)(Wh + (long)(n0+n)*160 + k0 + seg*8);
                }
            }
        }
        __syncthreads();

        bf16x8 ah[4], al[4];
#pragma unroll
        for (int mt=0;mt<4;mt++){
            int off = (wm*64 + mt*16 + ln)*40 + g*8;
            ah[mt] = *(const bf16x8*)(sAh + off);
            al[mt] = *(const bf16x8*)(sAl + off);
        }
#pragma unroll
        for (int nt=0;nt<5;nt++){
            int offw = (wn*80 + nt*16 + ln)*40 + g*8;
            bf16x8 bh = *(const bf16x8*)(sWh + offw);
#pragma unroll
            for (int mt=0;mt<4;mt++){
                acc[mt][nt] = __builtin_amdgcn_mfma_f32_16x16x32_bf16(ah[mt], bh, acc[mt][nt], 0,0,0);
                acc[mt][nt] = __builtin_amdgcn_mfma_f32_16x16x32_bf16(al[mt], bh, acc[mt][nt], 0,0,0);
            }
            if (SPLIT == 3){
                bf16x8 bl = *(const bf16x8*)(sWl + offw);
#pragma unroll
                for (int mt=0;mt<4;mt++)
                    acc[mt][nt] = __builtin_amdgcn_mfma_f32_16x16x32_bf16(ah[mt], bl, acc[mt][nt], 0,0,0);
            }
        }
        __syncthreads();
    }

#pragma unroll
    for (int nt=0;nt<5;nt++){
        int col = n0 + wn*80 + nt*16 + ln;
        float bv = bias[col];
#pragma unroll
        for (int mt=0;mt<4;mt++){
#pragma unroll
            for (int r=0;r<4;r++){
                long row = m0 + wm*64 + mt*16 + g*4 + r;
                float x = acc[mt][nt][r] + bv;
                if (EPI==1){
                    x = x > 0.f ? x : expm1f(x);
                    ((float*)(z ? C1v : C0v))[row*N + col] = x;
                } else {
                    ((ushort*)(z ? C1v : C0v))[row*N + col] = f2bf(x);
                }
            }
        }
    }
}

// ============================ bf16 GEMM (A bf16, W single-plane) ============
// C(M x N) = A(M x 160, bf16) @ W(N x 160, bf16)^T + bias -> bf16.
// 256 thr, tile 128M x 160N, k-chunks of 32. LDS 23 KB.
__global__ __launch_bounds__(NTH)
void gemm_bf(const ushort* __restrict__ A0, const ushort* __restrict__ A1,
             const ushort* __restrict__ Wh0, const ushort* __restrict__ Wh1,
             const float* __restrict__ b0, const float* __restrict__ b1,
             ushort* __restrict__ C0, ushort* __restrict__ C1, int N)
{
    const int z = blockIdx.z;
    const ushort* A  = z ? A1 : A0;
    const ushort* Wh = z ? Wh1 : Wh0;
    const float* bias = z ? b1 : b0;
    ushort* C = z ? C1 : C0;

    __shared__ ushort sA[128*40];
    __shared__ ushort sW[160*40];

    const int tid = threadIdx.x;
    const int lane = tid & 63, wave = tid >> 6;
    const int wm = wave >> 1, wn = wave & 1;
    const int ln = lane & 15, g = lane >> 4;
    const long m0 = (long)blockIdx.x * 128;
    const int  n0 = blockIdx.y * 160;

    f32x4 acc[4][5];
#pragma unroll
    for (int mt=0;mt<4;mt++)
#pragma unroll
        for (int nt=0;nt<5;nt++)
#pragma unroll
            for (int r=0;r<4;r++) acc[mt][nt][r] = 0.f;

    for (int k0=0;k0<160;k0+=32){
        // stage A chunk: 128 x 32 = 512 uint4
#pragma unroll
        for (int i=0;i<2;i++){
            int e = tid + 256*i;
            int m = e >> 2, seg = e & 3;
            *(uint4*)(sA + m*40 + seg*8) =
                *(const uint4*)(A + (m0+m)*160 + k0 + seg*8);
        }
        // stage W chunk: 160 x 32 = 640 uint4
#pragma unroll
        for (int i=0;i<3;i++){
            int e = tid + 256*i;
            if (e < 640){
                int n = e >> 2, seg = e & 3;
                *(uint4*)(sW + n*40 + seg*8) =
                    *(const uint4*)(Wh + (long)(n0+n)*160 + k0 + seg*8);
            }
        }
        __syncthreads();

        bf16x8 af[4];
#pragma unroll
        for (int mt=0;mt<4;mt++)
            af[mt] = *(const bf16x8*)(sA + (wm*64 + mt*16 + ln)*40 + g*8);
#pragma unroll
        for (int nt=0;nt<5;nt++){
            bf16x8 bh = *(const bf16x8*)(sW + (wn*80 + nt*16 + ln)*40 + g*8);
#pragma unroll
            for (int mt=0;mt<4;mt++)
                acc[mt][nt] = __builtin_amdgcn_mfma_f32_16x16x32_bf16(af[mt], bh, acc[mt][nt], 0,0,0);
        }
        __syncthreads();
    }

#pragma unroll
    for (int nt=0;nt<5;nt++){
        int col = n0 + wn*80 + nt*16 + ln;
        float bv = bias[col];
#pragma unroll
        for (int mt=0;mt<4;mt++){
#pragma unroll
            for (int r=0;r<4;r++){
                long row = m0 + wm*64 + mt*16 + g*4 + r;
                C[row*N + col] = f2bf(acc[mt][nt][r] + bv);
            }
        }
    }
}

// ============================ MFMA attention, layers 1/2 ============
__global__ __launch_bounds__(64)
void attn_layer_mfma(const ushort* __restrict__ XPi, const ushort* __restrict__ XPo,
                     const int* __restrict__ in_idx, const int* __restrict__ out_idx,
                     ushort* __restrict__ Oi, ushort* __restrict__ Oo, int node_base)
{
    const ushort* XP = blockIdx.y ? XPo : XPi;
    const int*  idx  = blockIdx.y ? out_idx : in_idx;
    ushort* O        = blockIdx.y ? Oo : Oi;

    __shared__ ushort XPg[16*496];
    __shared__ ushort Pall[5*16*24];

    const int lane = threadIdx.x;
    const int ln = lane & 15, q = lane >> 4;
    const int node = node_base + blockIdx.x;
    const int bb = node >> 12, nn = node & 4095;

    int idxv = nn;
    if (lane >= 1 && lane < 16) idxv = idx[(long)node*15 + lane-1];

#pragma unroll
    for (int i=0;i<15;i++){
        int e = lane + 64*i;
        int r = e/60, c = e - r*60;
        int rowg = __shfl(idxv, r);
        *(uint4*)(XPg + r*496 + c*8) =
            *(const uint4*)(XP + (long)(bb*4096 + rowg)*480 + c*8);
    }
    __syncthreads();

    const float scale = 0.17677669529663687f;
#pragma unroll
    for (int h=0;h<5;h++){
        bf16x8 ka = *(const bf16x8*)(XPg + ln*496 + 160 + h*32 + q*8);
        bf16x8 qb = *(const bf16x8*)(XPg + ln*496 +       h*32 + q*8);
        f32x4 s = {0.f,0.f,0.f,0.f};
        s = __builtin_amdgcn_mfma_f32_16x16x32_bf16(ka, qb, s, 0,0,0);
        float x[4], m = -1e30f;
#pragma unroll
        for (int r=0;r<4;r++){ x[r] = s[r]*scale; m = fmaxf(m, x[r]); }
        m = fmaxf(m, __shfl_xor(m, 16));
        m = fmaxf(m, __shfl_xor(m, 32));
        float e0[4], sum = 0.f;
#pragma unroll
        for (int r=0;r<4;r++){ e0[r] = __expf(x[r]-m); sum += e0[r]; }
        sum += __shfl_xor(sum, 16);
        sum += __shfl_xor(sum, 32);
        float inv = 1.f/sum;
        ushort4 pw;
        pw.x = f2bf(e0[0]*inv); pw.y = f2bf(e0[1]*inv);
        pw.z = f2bf(e0[2]*inv); pw.w = f2bf(e0[3]*inv);
        *(ushort4*)(Pall + h*384 + ln*24 + q*4) = pw;
    }
    __syncthreads();

#pragma unroll
    for (int h=0;h<5;h++){
        u16x8 ta;
#pragma unroll
        for (int jj=0;jj<8;jj++) ta[jj] = 0;
        if (q < 2) ta = *(const u16x8*)(Pall + h*384 + ln*24 + q*8);
        bf16x8 ap = *(bf16x8*)&ta;
#pragma unroll
        for (int half=0; half<2; half++){
            u16x8 tb;
#pragma unroll
            for (int jj=0;jj<8;jj++) tb[jj] = 0;
            if (q < 2){
#pragma unroll
                for (int jj=0;jj<8;jj++)
                    tb[jj] = XPg[(q*8+jj)*496 + 320 + h*32 + half*16 + ln];
            }
            bf16x8 bv = *(bf16x8*)&tb;
            f32x4 o = {0.f,0.f,0.f,0.f};
            o = __builtin_amdgcn_mfma_f32_16x16x32_bf16(ap, bv, o, 0,0,0);
#pragma unroll
            for (int r=0;r<4;r++)
                O[(long)(blockIdx.x*16 + q*4 + r)*160 + h*32 + half*16 + ln] = f2bf(o[r]);
        }
    }
}

// ============================ MFMA final attention ============
__global__ __launch_bounds__(64)
void attn_final_mfma(const ushort* __restrict__ FQi, const ushort* __restrict__ FQo,
                     ushort* __restrict__ O2)
{
    __shared__ ushort F[32*328];
    __shared__ ushort P[32*40];

    const int lane = threadIdx.x;
    const int ln = lane & 15, q = lane >> 4;
    const int nl = blockIdx.x;

#pragma unroll
    for (int i=0;i<20;i++){
        int e = lane + 64*i;
        int r = e/40, c = e - r*40;
        const ushort* src = (r<16) ? (FQi + (long)(nl*16+r)*480 + c*8)
                                   : (FQo + (long)(nl*16+r-16)*480 + c*8);
        *(uint4*)(F + r*328 + c*8) = *(const uint4*)src;
    }
    __syncthreads();

    f32x4 sc[2][2];
#pragma unroll
    for (int ti=0;ti<2;ti++)
#pragma unroll
        for (int tj=0;tj<2;tj++){
            f32x4 a = {0.f,0.f,0.f,0.f};
#pragma unroll
            for (int kc=0;kc<5;kc++){
                bf16x8 ka = *(const bf16x8*)(F + (tj*16+ln)*328 + 160 + kc*32 + q*8);
                bf16x8 qb = *(const bf16x8*)(F + (ti*16+ln)*328 +       kc*32 + q*8);
                a = __builtin_amdgcn_mfma_f32_16x16x32_bf16(ka, qb, a, 0,0,0);
            }
            sc[ti][tj] = a;
        }

    const float scale = 0.07905694150420949f;
#pragma unroll
    for (int ti=0;ti<2;ti++){
        float x[2][4], m = -1e30f;
#pragma unroll
        for (int tj=0;tj<2;tj++)
#pragma unroll
            for (int r=0;r<4;r++){ x[tj][r] = sc[ti][tj][r]*scale; m = fmaxf(m, x[tj][r]); }
        m = fmaxf(m, __shfl_xor(m, 16));
        m = fmaxf(m, __shfl_xor(m, 32));
        float sum = 0.f;
#pragma unroll
        for (int tj=0;tj<2;tj++)
#pragma unroll
            for (int r=0;r<4;r++){ x[tj][r] = __expf(x[tj][r]-m); sum += x[tj][r]; }
        sum += __shfl_xor(sum, 16);
        sum += __shfl_xor(sum, 32);
        float inv = 1.f/sum;
#pragma unroll
        for (int tj=0;tj<2;tj++){
            ushort4 pw;
            pw.x = f2bf(x[tj][0]*inv); pw.y = f2bf(x[tj][1]*inv);
            pw.z = f2bf(x[tj][2]*inv); pw.w = f2bf(x[tj][3]*inv);
            *(ushort4*)(P + (ti*16+ln)*40 + tj*16 + q*4) = pw;
        }
    }
    __syncthreads();

#pragma unroll
    for (int i=0;i<10;i++){
        int e = lane + 64*i;
        int r = e/20, c = e - r*20;
        const ushort* src = (r<16) ? (FQi + (long)(nl*16+r)*480 + 320 + c*8)
                                   : (FQo + (long)(nl*16+r-16)*480 + 320 + c*8);
        *(uint4*)(F + r*168 + c*8) = *(const uint4*)src;
    }
    __syncthreads();

    bf16x8 ap[2];
#pragma unroll
    for (int mi=0;mi<2;mi++)
        ap[mi] = *(const bf16x8*)(P + (mi*16+ln)*40 + q*8);
#pragma unroll
    for (int nt=0;nt<10;nt++){
        u16x8 tb;
#pragma unroll
        for (int jj=0;jj<8;jj++) tb[jj] = F[(q*8+jj)*168 + nt*16 + ln];
        bf16x8 bv = *(bf16x8*)&tb;
#pragma unroll
        for (int mi=0;mi<2;mi++){
            f32x4 o = {0.f,0.f,0.f,0.f};
            o = __builtin_amdgcn_mfma_f32_16x16x32_bf16(ap[mi], bv, o, 0,0,0);
#pragma unroll
            for (int r=0;r<4;r++)
                O2[(long)(nl*32 + mi*16 + q*4 + r)*160 + nt*16 + ln] = f2bf(o[r]);
        }
    }
}

// ============================ O3 GEMM + fused max-pool (single plane) ============
__global__ __launch_bounds__(512)
void gemm_o3pool(const ushort* __restrict__ A,
                 const ushort* __restrict__ Wh,
                 const float* __restrict__ fb, float* __restrict__ pooled,
                 int node_base)
{
    __shared__ ushort sA[128*168];
    __shared__ ushort sW[160*40];

    const int tid = threadIdx.x;
    const int lane = tid & 63, wave = tid >> 6;
    const int wm = wave >> 1, wn = wave & 1;
    const int ln = lane & 15, q = lane >> 4;
    const long m0 = (long)blockIdx.x * 128;

#pragma unroll
    for (int i=0;i<5;i++){
        int e = tid + 512*i;
        int m = e/20, s = e - m*20;
        *(uint4*)(sA + m*168 + s*8) = *(const uint4*)(A + (m0+m)*160 + s*8);
    }

    f32x4 acc[2][5];
#pragma unroll
    for (int mt=0;mt<2;mt++)
#pragma unroll
        for (int nt=0;nt<5;nt++)
#pragma unroll
            for (int r=0;r<4;r++) acc[mt][nt][r] = 0.f;

    for (int kc=0;kc<5;kc++){
        const int k0 = kc*32;
        __syncthreads();
        // stage W chunk: 160 x 32 = 640 uint4 — needs TWO passes at 512 thr
#pragma unroll
        for (int i=0;i<2;i++){
            int e = tid + 512*i;
            if (e < 640){
                int n = e >> 2, s = e & 3;
                *(uint4*)(sW + n*40 + s*8) =
                    *(const uint4*)(Wh + n*160 + k0 + s*8);
            }
        }
        __syncthreads();

        bf16x8 af[2];
#pragma unroll
        for (int mt=0;mt<2;mt++)
            af[mt] = *(const bf16x8*)(sA + (wm*32 + mt*16 + ln)*168 + k0 + q*8);
#pragma unroll
        for (int nt=0;nt<5;nt++){
            bf16x8 bh = *(const bf16x8*)(sW + (wn*80 + nt*16 + ln)*40 + q*8);
#pragma unroll
            for (int mt=0;mt<2;mt++)
                acc[mt][nt] = __builtin_amdgcn_mfma_f32_16x16x32_bf16(af[mt], bh, acc[mt][nt], 0,0,0);
        }
    }

    const int node = node_base + blockIdx.x*4 + wm;
#pragma unroll
    for (int nt=0;nt<5;nt++){
        float m = acc[0][nt][0];
#pragma unroll
        for (int mt=0;mt<2;mt++)
#pragma unroll
            for (int r=0;r<4;r++) m = fmaxf(m, acc[mt][nt][r]);
        m = fmaxf(m, __shfl_xor(m, 16));
        m = fmaxf(m, __shfl_xor(m, 32));
        if (q == 0){
            int col = wn*80 + nt*16 + ln;
            pooled[(long)node*160 + col] = m + fb[col];
        }
    }
}

// ============================ host ============================
extern "C" void kernel_launch(void* const* d_in, const int* in_sizes, int n_in,
                              void* d_out, int out_size, void* d_ws, size_t ws_size,
                              hipStream_t stream)
{
    const float* X       = (const float*)d_in[0];
    const int*   in_idx  = (const int*)  d_in[1];
    const int*   out_idx = (const int*)  d_in[2];
    const float* iWq     = (const float*)d_in[3];
    const float* iWk     = (const float*)d_in[4];
    const float* iWv     = (const float*)d_in[5];
    const float* i_in_w  = (const float*)d_in[6];
    const float* i_in_b  = (const float*)d_in[7];
    const float* i_out_w = (const float*)d_in[8];
    const float* i_out_b = (const float*)d_in[9];
    const float* oWq     = (const float*)d_in[10];
    const float* oWk     = (const float*)d_in[11];
    const float* oWv     = (const float*)d_in[12];
    const float* o_in_w  = (const float*)d_in[13];
    const float* o_in_b  = (const float*)d_in[14];
    const float* o_out_w = (const float*)d_in[15];
    const float* o_out_b = (const float*)d_in[16];
    const float* f_in_w  = (const float*)d_in[17];
    const float* f_in_b  = (const float*)d_in[18];
    const float* f_out_w = (const float*)d_in[19];
    const float* f_out_b = (const float*)d_in[20];
    const float* lin_w   = (const float*)d_in[21];
    const float* lin_b   = (const float*)d_in[22];

    float* ws = (float*)d_ws;
    float* pooled = ws;                           // 32768*160 fp32
    float* c_i    = pooled + 5242880;             // 480
    float* c_o    = c_i + 480;
    ushort* ub    = (ushort*)(c_o + 480);
    ushort* XPb_i = ub;                           // 32768*480 bf16
    ushort* XPb_o = XPb_i + 15728640;
    ushort* Wci_h = XPb_o + 15728640;             // 76800 each
    ushort* Wco_h = Wci_h + 76800;
    ushort* Hi_h  = Wco_h + 76800;
    ushort* Ho_h  = Hi_h  + 76800;
    ushort* fo_h  = Ho_h  + 76800;                // 25600 each
    ushort* li_h  = fo_h  + 25600;
    ushort* li_l  = li_h  + 25600;
    ushort* sb_us = li_l + 25600;
    const unsigned long long fixed = 21164480ULL;   // floats

    size_t avail = ws_size / 4;
    int ns = 4096;
    while (ns > 64 && fixed + 12800ULL*ns > avail) ns >>= 1;

    ushort* O_i = sb_us;                          // ns*16*160
    ushort* O_o = O_i + (size_t)2560*ns;
    ushort* FQi = O_o + (size_t)2560*ns;          // ns*16*480
    ushort* FQo = FQi + (size_t)7680*ns;
    ushort* O2  = FQo + (size_t)7680*ns;          // ns*32*160

    prep_combined_bf<<<300,NTH,0,stream>>>(iWq,iWk,iWv,i_in_w, Wci_h);
    prep_combined_bf<<<300,NTH,0,stream>>>(oWq,oWk,oWv,o_in_w, Wco_h);
    prep_H_bf<<<300,NTH,0,stream>>>(f_in_w, i_out_w, Hi_h);
    prep_H_bf<<<300,NTH,0,stream>>>(f_in_w, o_out_w, Ho_h);
    prep_cvec<<<2,NTH,0,stream>>>(f_in_w, i_out_b, f_in_b, c_i);
    prep_cvec<<<2,NTH,0,stream>>>(f_in_w, o_out_b, f_in_b, c_o);
    prep_conv_bf1<<<100,NTH,0,stream>>>(f_out_w, fo_h, 25600);
    prep_conv_bf2<<<100,NTH,0,stream>>>(lin_w,   li_h, li_l, 25600);

    // XP = X @ Wc^T + in_b  -> bf16 (split-x2; both layers via z)
    dim3 g1(256, 3, 2);
    gemm_mfma<2,2><<<g1,NTH,0,stream>>>(X, X, Wci_h, nullptr, Wco_h, nullptr,
                                        i_in_b, o_in_b, XPb_i, XPb_o, 480);

    int S = 32768 / ns;
    for (int s=0;s<S;s++){
        int base = s*ns;
        dim3 ga(ns, 2);
        attn_layer_mfma<<<ga,64,0,stream>>>(XPb_i, XPb_o, in_idx, out_idx, O_i, O_o, base);
        dim3 g3(ns/8, 3, 2);
        gemm_bf<<<g3,NTH,0,stream>>>(O_i, O_o, Hi_h, Ho_h, c_i, c_o, FQi, FQo, 480);
        attn_final_mfma<<<ns,64,0,stream>>>(FQi, FQo, O2);
        gemm_o3pool<<<ns/4,512,0,stream>>>(O2, fo_h, f_out_b, pooled, base);
    }

    // out = ELU(pooled @ lin_w^T + lin_b)  fp32, split-x3
    dim3 g6(256, 1, 1);
    gemm_mfma<1,3><<<g6,NTH,0,stream>>>(pooled, pooled, li_h, li_l, li_h, li_l,
                                        lin_b, lin_b, d_out, d_out, 160);
}